// Round 9
// baseline (154.424 us; speedup 1.0000x reference)
//
#include <hip/hip_runtime.h>
#include <hip/hip_fp16.h>
#include <math.h>

#define Wd 512
#define Hd 512
#define Bd 32
#define PLANE (Hd * Wd)

// k_rotate: 16x16 tile; rotated window 26x26, SoA f32 x4 planes in LDS.
#define WND 26
#define PLSTR (WND * WND)        // 676 floats per plane
#define NS1 (4 * PLSTR)          // 2704 dword slots (11 issues/thread)

// k_affine: 32x16 tile; window 22 rows x 40 cols of fp16 AoS cells (20 pairs).
#define RPW 40
#define RPH 22
#define NP2 (RPH * (RPW / 2))    // 440 pair slots (2 issues/thread)

__device__ __forceinline__ float clip01(float x) { return fminf(fmaxf(x, 0.f), 1.f); }

__device__ __forceinline__ unsigned pack2h(float a, float b) {
    __half2 h = __floats2half2_rn(a, b);
    return *(unsigned*)&h;
}
__device__ __forceinline__ float2 unp2h(unsigned u) {
    return __half22float2(*(__half2*)&u);
}

// global->LDS DMA (no VGPR round trip). Dest = wave-uniform base + lane*size;
// our slot maps are lane-linear with suffix-only masking, so layout matches.
__device__ __forceinline__ void gload_lds4(const void* g, void* l) {
    __builtin_amdgcn_global_load_lds(
        (const __attribute__((address_space(1))) unsigned int*)g,
        (__attribute__((address_space(3))) unsigned int*)l, 4, 0, 0);
}
__device__ __forceinline__ void gload_lds16(const void* g, void* l) {
    __builtin_amdgcn_global_load_lds(
        (const __attribute__((address_space(1))) unsigned int*)g,
        (__attribute__((address_space(3))) unsigned int*)l, 16, 0, 0);
}

// ---------------------------------------------------------------------------
// K1: flip(+)rotate fused -> AoS fp16 rot. Flips folded as coordinate
// reflection (sx' = 511-sx). DMA staging with CLAMPED addresses; zero-padding
// semantics enforced by validity-weight masking at sample time (== reference).
// ---------------------------------------------------------------------------
__global__ __launch_bounds__(256) void k_rotate(const float* __restrict__ imgs,
                                                const float* __restrict__ masks,
                                                const int* __restrict__ hflip,
                                                const int* __restrict__ vflip,
                                                const float* __restrict__ angles,
                                                uint2* __restrict__ rot)
{
    __shared__ float sP[NS1];            // 10816 B: 4 planes SoA, row stride WND

    const int tx = threadIdx.x, ty = threadIdx.y;
    const int tid = ty * 16 + tx;
    const int bx = blockIdx.x * 16, by = blockIdx.y * 16;
    const int b = blockIdx.z;

    const float cx = (Wd - 1) * 0.5f, cy = (Hd - 1) * 0.5f;
    const float th = angles[b] * 0.017453292519943295f;
    const float c = cosf(th), s = sinf(th);
    const bool hf = hflip[b] > 0, vf = vflip[b] > 0;

    // tile-corner bbox (same fp expressions as per-pixel, incl. reflection)
    const float xs0 = (float)bx - cx, xs1 = (float)(bx + 15) - cx;
    const float ys0 = (float)by - cy, ys1 = (float)(by + 15) - cy;
    float a0 = c * xs0 + s * ys0 + cx, a1 = c * xs1 + s * ys0 + cx;
    float a2 = c * xs0 + s * ys1 + cx, a3 = c * xs1 + s * ys1 + cx;
    float b0 = -s * xs0 + c * ys0 + cy, b1 = -s * xs1 + c * ys0 + cy;
    float b2 = -s * xs0 + c * ys1 + cy, b3 = -s * xs1 + c * ys1 + cy;
    float mnx = fminf(fminf(a0, a1), fminf(a2, a3));
    float mxx = fmaxf(fmaxf(a0, a1), fmaxf(a2, a3));
    float mny = fminf(fminf(b0, b1), fminf(b2, b3));
    float mxy = fmaxf(fmaxf(b0, b1), fmaxf(b2, b3));
    const int ox0 = (int)floorf(hf ? (511.f - mxx) : mnx) - 1;
    const int oy0 = (int)floorf(vf ? (511.f - mxy) : mny) - 1;

    const float* ib = imgs + (size_t)b * 3 * PLANE;
    const float* mb = masks + (size_t)b * PLANE;

    // ---- DMA staging: 11 width-4 issues/thread, clamped source addrs ----
    #pragma unroll
    for (int it = 0; it < 11; ++it) {
        int slot = tid + it * 256;
        if (slot < NS1) {                     // suffix-only masking
            int p    = slot / PLSTR;
            int cell = slot - p * PLSTR;
            int row  = cell / WND;
            int col  = cell - row * WND;
            int gy = min(max(oy0 + row, 0), Hd - 1);
            int gx = min(max(ox0 + col, 0), Wd - 1);
            const float* sp = (p == 3) ? mb : ib + p * PLANE;
            gload_lds4(sp + gy * Wd + gx, &sP[slot]);
        }
    }
    __syncthreads();                          // compiler drains vmcnt here

    const int x = bx + tx, y = by + ty;
    float dx = (float)x - cx, dy = (float)y - cy;
    float sx = c * dx + s * dy + cx;
    float sy = -s * dx + c * dy + cy;
    if (hf) sx = 511.f - sx;
    if (vf) sy = 511.f - sy;

    float sxl = sx - (float)ox0, syl = sy - (float)oy0;
    float x0f = floorf(sxl), y0f = floorf(syl);
    float wx = sxl - x0f, wy = syl - y0f;
    int xi = min(max((int)x0f, 0), WND - 2);
    int yi = min(max((int)y0f, 0), WND - 2);

    // validity from true source coords (reference's valid-mask semantics)
    float fx0 = (float)ox0 + x0f, fy0 = (float)oy0 + y0f;
    float vx0 = (fx0 >= 0.f && fx0 <= 511.f) ? 1.f : 0.f;
    float vx1 = (fx0 >= -1.f && fx0 <= 510.f) ? 1.f : 0.f;
    float vy0 = (fy0 >= 0.f && fy0 <= 511.f) ? 1.f : 0.f;
    float vy1 = (fy0 >= -1.f && fy0 <= 510.f) ? 1.f : 0.f;
    float w00 = (1.f - wx) * (1.f - wy) * vx0 * vy0;
    float w10 = wx * (1.f - wy) * vx1 * vy0;
    float w01 = (1.f - wx) * wy * vx0 * vy1;
    float w11 = wx * wy * vx1 * vy1;

    int base = yi * WND + xi;
    float r  = w00 * sP[base]             + w10 * sP[base + 1]
             + w01 * sP[base + WND]       + w11 * sP[base + WND + 1];
    float g  = w00 * sP[base + PLSTR]     + w10 * sP[base + PLSTR + 1]
             + w01 * sP[base + PLSTR + WND] + w11 * sP[base + PLSTR + WND + 1];
    float bl = w00 * sP[base + 2*PLSTR]   + w10 * sP[base + 2*PLSTR + 1]
             + w01 * sP[base + 2*PLSTR + WND] + w11 * sP[base + 2*PLSTR + WND + 1];
    float m  = w00 * sP[base + 3*PLSTR]   + w10 * sP[base + 3*PLSTR + 1]
             + w01 * sP[base + 3*PLSTR + WND] + w11 * sP[base + 3*PLSTR + WND + 1];

    rot[(size_t)b * PLANE + (size_t)y * Wd + x] =
        make_uint2(pack2h(r, g), pack2h(bl, m));
}

// ---------------------------------------------------------------------------
// K2: affine from AoS fp16 rot + brightness. DMA pair-staging (width 16,
// even-aligned pair base, clamped) + validity-weight masking. Writes masks
// (final f32) to d_out, rgb as packed fp16 planes to ws, gray partials.
// ---------------------------------------------------------------------------
__global__ __launch_bounds__(256) void k_affine(const uint2* __restrict__ rot,
                                                const float* __restrict__ translate,
                                                const float* __restrict__ scale,
                                                const float* __restrict__ brightness,
                                                unsigned short* __restrict__ pre,
                                                float* __restrict__ omasks,
                                                float* __restrict__ partials)
{
    __shared__ uint4 stag[NP2];          // 7040 B
    const uint2* cells = (const uint2*)stag;

    const int tx2 = threadIdx.x;         // 0..15
    const int ty  = threadIdx.y;         // 0..15
    const int tid = ty * 16 + tx2;
    const int bx = blockIdx.x * 32, by = blockIdx.y * 16;
    const int b = blockIdx.z;

    const float cx = (Wd - 1) * 0.5f, cy = (Hd - 1) * 0.5f;
    const float txf = translate[2 * b] * (float)Wd;
    const float tyf = translate[2 * b + 1] * (float)Hd;
    const float sc = scale[b];
    const float bf = brightness[b];

    float ax0 = ((float)bx - cx - txf) / sc + cx;
    float ax1 = ((float)(bx + 31) - cx - txf) / sc + cx;
    float ay0 = ((float)by - cy - tyf) / sc + cy;
    float ay1 = ((float)(by + 15) - cy - tyf) / sc + cy;
    const int rx0 = (int)floorf(fminf(ax0, ax1)) - 1;
    const int ry0 = (int)floorf(fminf(ay0, ay1)) - 1;
    const int rxE = rx0 & ~1;            // even pair-aligned window origin

    const uint2* sb = rot + (size_t)b * PLANE;

    #pragma unroll
    for (int it = 0; it < 2; ++it) {
        int slot = tid + it * 256;
        if (slot < NP2) {
            int row = slot / (RPW / 2);
            int pr  = slot - row * (RPW / 2);
            int gy = min(max(ry0 + row, 0), Hd - 1);
            int gx = min(max(rxE + pr * 2, 0), Wd - 2) & ~1;
            gload_lds16(sb + gy * Wd + gx, &stag[slot]);
        }
    }
    __syncthreads();

    float grays = 0.f;
    float rr[2], gg[2], bb[2], mm[2];
    #pragma unroll
    for (int k = 0; k < 2; ++k) {
        int x = bx + 2 * tx2 + k, y = by + ty;
        float sx = ((float)x - cx - txf) / sc + cx;
        float sy = ((float)y - cy - tyf) / sc + cy;
        float sxl = sx - (float)rxE, syl = sy - (float)ry0;
        float x0f = floorf(sxl), y0f = floorf(syl);
        float wx = sxl - x0f, wy = syl - y0f;
        int xi = min(max((int)x0f, 0), RPW - 2);
        int yi = min(max((int)y0f, 0), RPH - 2);

        float fx0 = (float)rxE + x0f, fy0 = (float)ry0 + y0f;
        float vx0 = (fx0 >= 0.f && fx0 <= 511.f) ? 1.f : 0.f;
        float vx1 = (fx0 >= -1.f && fx0 <= 510.f) ? 1.f : 0.f;
        float vy0 = (fy0 >= 0.f && fy0 <= 511.f) ? 1.f : 0.f;
        float vy1 = (fy0 >= -1.f && fy0 <= 510.f) ? 1.f : 0.f;
        float w00 = (1.f - wx) * (1.f - wy) * vx0 * vy0;
        float w10 = wx * (1.f - wy) * vx1 * vy0;
        float w01 = (1.f - wx) * wy * vx0 * vy1;
        float w11 = wx * wy * vx1 * vy1;

        int base = yi * RPW + xi;
        uint2 c00 = cells[base],        c10 = cells[base + 1];
        uint2 c01 = cells[base + RPW],  c11 = cells[base + RPW + 1];
        float2 rg00 = unp2h(c00.x), bm00 = unp2h(c00.y);
        float2 rg10 = unp2h(c10.x), bm10 = unp2h(c10.y);
        float2 rg01 = unp2h(c01.x), bm01 = unp2h(c01.y);
        float2 rg11 = unp2h(c11.x), bm11 = unp2h(c11.y);

        float r  = w00 * rg00.x + w10 * rg10.x + w01 * rg01.x + w11 * rg11.x;
        float g  = w00 * rg00.y + w10 * rg10.y + w01 * rg01.y + w11 * rg11.y;
        float b2 = w00 * bm00.x + w10 * bm10.x + w01 * bm01.x + w11 * bm11.x;
        float m  = w00 * bm00.y + w10 * bm10.y + w01 * bm01.y + w11 * bm11.y;

        r = clip01(r * bf);
        g = clip01(g * bf);
        b2 = clip01(b2 * bf);
        rr[k] = r; gg[k] = g; bb[k] = b2; mm[k] = m;
        grays += 0.299f * r + 0.587f * g + 0.114f * b2;
    }
    {
        size_t pix = (size_t)(by + ty) * Wd + bx + 2 * tx2;       // even
        unsigned short* pb = pre + (size_t)b * 3 * PLANE;
        *(unsigned*)(pb + pix)             = pack2h(rr[0], rr[1]);
        *(unsigned*)(pb + PLANE + pix)     = pack2h(gg[0], gg[1]);
        *(unsigned*)(pb + 2 * PLANE + pix) = pack2h(bb[0], bb[1]);
        *(float2*)(omasks + (size_t)b * PLANE + pix) = make_float2(mm[0], mm[1]);
    }

    __syncthreads();
    float* sred = (float*)stag;
    sred[tid] = grays;
    __syncthreads();
    for (int off = 128; off > 0; off >>= 1) {
        if (tid < off) sred[tid] += sred[tid + off];
        __syncthreads();
    }
    if (tid == 0)
        partials[(size_t)b * 512 + blockIdx.y * 16 + blockIdx.x] = sred[0];
}

__global__ __launch_bounds__(256) void k_mean(const float* __restrict__ partials,
                                              float* __restrict__ means)
{
    int b = blockIdx.x;
    int t = threadIdx.x;
    float s = partials[(size_t)b * 512 + t] + partials[(size_t)b * 512 + t + 256];
    __shared__ float sr[256];
    sr[t] = s;
    __syncthreads();
    for (int off = 128; off > 0; off >>= 1) {
        if (t < off) sr[t] += sr[t + off];
        __syncthreads();
    }
    if (t == 0) means[b] = sr[0] * (1.f / (float)PLANE);
}

__device__ __forceinline__ void jit1(float& r, float& g, float& bl,
                                     float mean, float cf, float sf, float hsh)
{
    r  = clip01(cf * r + (1.f - cf) * mean);
    g  = clip01(cf * g + (1.f - cf) * mean);
    bl = clip01(cf * bl + (1.f - cf) * mean);

    float gray = 0.299f * r + 0.587f * g + 0.114f * bl;
    r  = clip01(sf * r + (1.f - sf) * gray);
    g  = clip01(sf * g + (1.f - sf) * gray);
    bl = clip01(sf * bl + (1.f - sf) * gray);

    float maxc = fmaxf(fmaxf(r, g), bl);
    float minc = fminf(fminf(r, g), bl);
    float delta = maxc - minc;
    float sgm = delta / (maxc + 1e-8f);
    float dd = delta + 1e-8f;
    float rc = (maxc - r) / dd;
    float gc = (maxc - g) / dd;
    float bc = (maxc - bl) / dd;
    float h6 = (maxc == r) ? (bc - gc) : ((maxc == g) ? (2.f + rc - bc) : (4.f + gc - rc));
    float h = h6 * (1.f / 6.f);
    h = h - floorf(h);
    h = h + hsh;
    h = h - floorf(h);

    float hi = floorf(h * 6.f);
    float f = h * 6.f - hi;
    float v = maxc;
    float p = v * (1.f - sgm);
    float q = v * (1.f - f * sgm);
    float t = v * (1.f - (1.f - f) * sgm);
    int i = ((int)hi) % 6;
    if (i < 0) i += 6;
    float ro, go, bo;
    switch (i) {
        case 0: ro = v; go = t; bo = p; break;
        case 1: ro = q; go = v; bo = p; break;
        case 2: ro = p; go = v; bo = t; break;
        case 3: ro = p; go = q; bo = v; break;
        case 4: ro = t; go = p; bo = v; break;
        default: ro = v; go = p; bo = q; break;
    }
    r = clip01(ro); g = clip01(go); bl = clip01(bo);
}

__global__ __launch_bounds__(256) void k_jitter(const unsigned short* __restrict__ pre,
                                                const float* __restrict__ means,
                                                const float* __restrict__ contrast,
                                                const float* __restrict__ saturation,
                                                const float* __restrict__ hue,
                                                float* __restrict__ oimgs)
{
    int b = blockIdx.y;
    size_t i4 = (size_t)blockIdx.x * 256 + threadIdx.x;   // group of 4 px
    const unsigned short* pb = pre + (size_t)b * 3 * PLANE;

    uint2 ur = *(const uint2*)(pb + i4 * 4);
    uint2 ug = *(const uint2*)(pb + PLANE + i4 * 4);
    uint2 ub = *(const uint2*)(pb + 2 * PLANE + i4 * 4);

    float2 r01 = unp2h(ur.x), r23 = unp2h(ur.y);
    float2 g01 = unp2h(ug.x), g23 = unp2h(ug.y);
    float2 b01 = unp2h(ub.x), b23 = unp2h(ub.y);

    float4 R  = make_float4(r01.x, r01.y, r23.x, r23.y);
    float4 G  = make_float4(g01.x, g01.y, g23.x, g23.y);
    float4 Bv = make_float4(b01.x, b01.y, b23.x, b23.y);

    float mean = means[b];
    float cf = contrast[b], sf = saturation[b], hsh = hue[b];

    jit1(R.x, G.x, Bv.x, mean, cf, sf, hsh);
    jit1(R.y, G.y, Bv.y, mean, cf, sf, hsh);
    jit1(R.z, G.z, Bv.z, mean, cf, sf, hsh);
    jit1(R.w, G.w, Bv.w, mean, cf, sf, hsh);

    size_t po = (size_t)b * 3 * PLANE + i4 * 4;
    *(float4*)(oimgs + po)             = R;
    *(float4*)(oimgs + po + PLANE)     = G;
    *(float4*)(oimgs + po + 2 * PLANE) = Bv;
}

extern "C" void kernel_launch(void* const* d_in, const int* in_sizes, int n_in,
                              void* d_out, int out_size, void* d_ws, size_t ws_size,
                              hipStream_t stream)
{
    const float* imgs       = (const float*)d_in[0];
    const float* masks      = (const float*)d_in[1];
    const int*   hflip      = (const int*)d_in[2];
    const int*   vflip      = (const int*)d_in[3];
    const float* angles     = (const float*)d_in[4];
    const float* translate  = (const float*)d_in[5];
    const float* scale      = (const float*)d_in[6];
    const float* brightness = (const float*)d_in[7];
    const float* contrast   = (const float*)d_in[8];
    const float* saturation = (const float*)d_in[9];
    const float* hue        = (const float*)d_in[10];

    float* oimgs  = (float*)d_out;
    float* omasks = oimgs + (size_t)Bd * 3 * PLANE;

    uint2* rot          = (uint2*)d_ws;                                  // 67 MB
    unsigned short* pre = (unsigned short*)(rot + (size_t)Bd * PLANE);   // 50 MB
    float* partials     = (float*)(pre + (size_t)3 * Bd * PLANE);        // Bd*512
    float* means        = partials + (size_t)Bd * 512;                   // Bd

    dim3 blk1(16, 16);
    dim3 grd1(Wd / 16, Hd / 16, Bd);
    k_rotate<<<grd1, blk1, 0, stream>>>(imgs, masks, hflip, vflip, angles, rot);

    dim3 blk2(16, 16);
    dim3 grd2(Wd / 32, Hd / 16, Bd);
    k_affine<<<grd2, blk2, 0, stream>>>(rot, translate, scale, brightness,
                                        pre, omasks, partials);

    k_mean<<<Bd, 256, 0, stream>>>(partials, means);

    dim3 grd3(PLANE / 4 / 256, Bd);
    k_jitter<<<grd3, 256, 0, stream>>>(pre, means, contrast, saturation, hue, oimgs);
}

// Round 10
// 154.021 us; speedup vs baseline: 1.0026x; 1.0026x over previous
//
#include <hip/hip_runtime.h>
#include <hip/hip_fp16.h>
#include <math.h>

#define Wd 512
#define Hd 512
#define Bd 32
#define PLANE (Hd * Wd)

// k_rotate: 16x16 tile; window 26 rows x 32 cols (4-aligned origin, 26 needed
// + up to 3 align slack). LDS AoS float4 cells, row stride 33 (odd*16B).
#define WNDR 26
#define WNDC 32
#define LSTR 33
#define NCHK (WNDR * (WNDC / 4) * 4)   // 832 float4 chunk-loads (4 planes)

// k_affine staging window (AoS float4 cells); scale>=0.9 -> cols<=39, rows<=21
#define RPW 40
#define RPH 22

__device__ __forceinline__ float clip01(float x) { return fminf(fmaxf(x, 0.f), 1.f); }

__device__ __forceinline__ unsigned pack2h(float a, float b) {
    __half2 h = __floats2half2_rn(a, b);
    return *(unsigned*)&h;
}
__device__ __forceinline__ float2 unp2h(unsigned u) {
    return __half22float2(*(__half2*)&u);
}

// ---------------------------------------------------------------------------
// K1: flip + rotate -> AoS fp16 rot. Flips folded as coordinate reflection.
// Staging: float4 row-chunks from f32 planes (4x fewer addresses than scalar),
// clamped addresses (aligned chunks are all-in or all-OOB); zero-padding
// enforced via validity-weight masking at sample time.
// ---------------------------------------------------------------------------
__global__ __launch_bounds__(256) void k_rotate(const float* __restrict__ imgs,
                                                const float* __restrict__ masks,
                                                const int* __restrict__ hflip,
                                                const int* __restrict__ vflip,
                                                const float* __restrict__ angles,
                                                uint2* __restrict__ rot)
{
    __shared__ float4 tile[WNDR * LSTR];   // 13728 B

    const int tx = threadIdx.x, ty = threadIdx.y;
    const int tid = ty * 16 + tx;
    const int bx = blockIdx.x * 16, by = blockIdx.y * 16;
    const int b = blockIdx.z;

    const float cx = (Wd - 1) * 0.5f, cy = (Hd - 1) * 0.5f;
    const float th = angles[b] * 0.017453292519943295f;
    const float c = cosf(th), s = sinf(th);
    const bool hf = hflip[b] > 0, vf = vflip[b] > 0;

    // tile-corner bbox (same fp expressions as per-pixel, incl. reflection)
    const float xs0 = (float)bx - cx, xs1 = (float)(bx + 15) - cx;
    const float ys0 = (float)by - cy, ys1 = (float)(by + 15) - cy;
    float a0 = c * xs0 + s * ys0 + cx, a1 = c * xs1 + s * ys0 + cx;
    float a2 = c * xs0 + s * ys1 + cx, a3 = c * xs1 + s * ys1 + cx;
    float b0 = -s * xs0 + c * ys0 + cy, b1 = -s * xs1 + c * ys0 + cy;
    float b2 = -s * xs0 + c * ys1 + cy, b3 = -s * xs1 + c * ys1 + cy;
    float mnx = fminf(fminf(a0, a1), fminf(a2, a3));
    float mxx = fmaxf(fmaxf(a0, a1), fmaxf(a2, a3));
    float mny = fminf(fminf(b0, b1), fminf(b2, b3));
    float mxy = fmaxf(fmaxf(b0, b1), fmaxf(b2, b3));
    const int ox0 = (int)floorf(hf ? (511.f - mxx) : mnx) - 1;
    const int oy0 = (int)floorf(vf ? (511.f - mxy) : mny) - 1;
    const int oxa = ox0 & ~3;              // 4-aligned window origin

    const float* ib = imgs + (size_t)b * 3 * PLANE;
    const float* mb = masks + (size_t)b * PLANE;

    // ---- staging: 832 float4 chunk loads; planar -> AoS transpose in LDS ----
    for (int slot = tid; slot < NCHK; slot += 256) {
        int p    = slot >> 8;                      // /208? no: see mapping below
        // mapping: slot = p*208 + row*8 + ch  (208 = 26*8)
        p = slot / 208;
        int rem  = slot - p * 208;
        int row  = rem >> 3;
        int ch   = rem & 7;
        int gy = min(max(oy0 + row, 0), Hd - 1);
        int gxc = min(max(oxa + ch * 4, 0), Wd - 4);   // stays 4-aligned
        const float* sp = (p == 3) ? mb : ib + p * PLANE;
        float4 v = *(const float4*)(sp + gy * Wd + gxc);
        float* cell = (float*)&tile[row * LSTR + ch * 4];   // 4 consecutive cells
        cell[p]      = v.x;       // component p of cell ch*4+0
        cell[4 + p]  = v.y;
        cell[8 + p]  = v.z;
        cell[12 + p] = v.w;
    }
    __syncthreads();

    const int x = bx + tx, y = by + ty;
    float dx = (float)x - cx, dy = (float)y - cy;
    float sx = c * dx + s * dy + cx;
    float sy = -s * dx + c * dy + cy;
    if (hf) sx = 511.f - sx;
    if (vf) sy = 511.f - sy;

    float sxl = sx - (float)oxa, syl = sy - (float)oy0;
    float x0f = floorf(sxl), y0f = floorf(syl);
    float wx = sxl - x0f, wy = syl - y0f;
    int xi = min(max((int)x0f, 0), WNDC - 2);
    int yi = min(max((int)y0f, 0), WNDR - 2);

    // validity from true source coords (reference's valid-mask semantics)
    float fx0 = (float)oxa + x0f, fy0 = (float)oy0 + y0f;
    float vx0 = (fx0 >= 0.f && fx0 <= 511.f) ? 1.f : 0.f;
    float vx1 = (fx0 >= -1.f && fx0 <= 510.f) ? 1.f : 0.f;
    float vy0 = (fy0 >= 0.f && fy0 <= 511.f) ? 1.f : 0.f;
    float vy1 = (fy0 >= -1.f && fy0 <= 510.f) ? 1.f : 0.f;
    float w00 = (1.f - wx) * (1.f - wy) * vx0 * vy0;
    float w10 = wx * (1.f - wy) * vx1 * vy0;
    float w01 = (1.f - wx) * wy * vx0 * vy1;
    float w11 = wx * wy * vx1 * vy1;

    int base = yi * LSTR + xi;
    float4 v00 = tile[base], v10 = tile[base + 1];
    float4 v01 = tile[base + LSTR], v11 = tile[base + LSTR + 1];

    float r  = w00 * v00.x + w10 * v10.x + w01 * v01.x + w11 * v11.x;
    float g  = w00 * v00.y + w10 * v10.y + w01 * v01.y + w11 * v11.y;
    float bl = w00 * v00.z + w10 * v10.z + w01 * v01.z + w11 * v11.z;
    float m  = w00 * v00.w + w10 * v10.w + w01 * v01.w + w11 * v11.w;

    rot[(size_t)b * PLANE + (size_t)y * Wd + x] =
        make_uint2(pack2h(r, g), pack2h(bl, m));
}

// ---------------------------------------------------------------------------
// K2: affine from AoS fp16 rot + brightness (register staging, R7-proven).
// Writes masks (final f32) to d_out, rgb as packed fp16 planes to ws, partials.
// ---------------------------------------------------------------------------
__global__ __launch_bounds__(256) void k_affine(const ushort4* __restrict__ rot,
                                                const float* __restrict__ translate,
                                                const float* __restrict__ scale,
                                                const float* __restrict__ brightness,
                                                unsigned short* __restrict__ pre,
                                                float* __restrict__ omasks,
                                                float* __restrict__ partials)
{
    __shared__ float4 tile[RPH * RPW];     // 14080 B

    const int tx2 = threadIdx.x;           // 0..15
    const int ty  = threadIdx.y;           // 0..15
    const int tid = ty * 16 + tx2;
    const int bx = blockIdx.x * 32, by = blockIdx.y * 16;
    const int b = blockIdx.z;

    const float cx = (Wd - 1) * 0.5f, cy = (Hd - 1) * 0.5f;
    const float txf = translate[2 * b] * (float)Wd;
    const float tyf = translate[2 * b + 1] * (float)Hd;
    const float sc = scale[b];
    const float bf = brightness[b];

    float ax0 = ((float)bx - cx - txf) / sc + cx;
    float ax1 = ((float)(bx + 31) - cx - txf) / sc + cx;
    float ay0 = ((float)by - cy - tyf) / sc + cy;
    float ay1 = ((float)(by + 15) - cy - tyf) / sc + cy;
    const int rx0 = (int)floorf(fminf(ax0, ax1)) - 1;
    const int ry0 = (int)floorf(fminf(ay0, ay1)) - 1;

    const ushort4* srcp = rot + (size_t)b * PLANE;
    const bool fastp = (rx0 >= 0) && (ry0 >= 0) &&
                       (rx0 + RPW <= Wd) && (ry0 + RPH <= Hd);

    if (fastp) {
        for (int idx = tid; idx < RPH * RPW; idx += 256) {
            int row = idx / RPW;
            int col = idx - row * RPW;
            ushort4 h = srcp[(ry0 + row) * Wd + rx0 + col];
            tile[idx] = make_float4(__half2float(__ushort_as_half(h.x)),
                                    __half2float(__ushort_as_half(h.y)),
                                    __half2float(__ushort_as_half(h.z)),
                                    __half2float(__ushort_as_half(h.w)));
        }
    } else {
        for (int idx = tid; idx < RPH * RPW; idx += 256) {
            int row = idx / RPW;
            int col = idx - row * RPW;
            int gy = ry0 + row, gx = rx0 + col;
            float4 v = make_float4(0.f, 0.f, 0.f, 0.f);
            if ((unsigned)gy < (unsigned)Hd && (unsigned)gx < (unsigned)Wd) {
                ushort4 h = srcp[gy * Wd + gx];
                v = make_float4(__half2float(__ushort_as_half(h.x)),
                                __half2float(__ushort_as_half(h.y)),
                                __half2float(__ushort_as_half(h.z)),
                                __half2float(__ushort_as_half(h.w)));
            }
            tile[idx] = v;
        }
    }
    __syncthreads();

    float grays = 0.f;
    float rr[2], gg[2], bb[2], mm[2];
    #pragma unroll
    for (int k = 0; k < 2; ++k) {
        int x = bx + 2 * tx2 + k, y = by + ty;
        float sx = ((float)x - cx - txf) / sc + cx;
        float sy = ((float)y - cy - tyf) / sc + cy;
        float sxl = sx - (float)rx0, syl = sy - (float)ry0;
        float x0f = floorf(sxl), y0f = floorf(syl);
        float wx = sxl - x0f, wy = syl - y0f;
        int xi = min(max((int)x0f, 0), RPW - 2);
        int yi = min(max((int)y0f, 0), RPH - 2);
        float w00 = (1.f - wx) * (1.f - wy);
        float w10 = wx * (1.f - wy);
        float w01 = (1.f - wx) * wy;
        float w11 = wx * wy;
        int base = yi * RPW + xi;
        float4 v00 = tile[base], v10 = tile[base + 1];
        float4 v01 = tile[base + RPW], v11 = tile[base + RPW + 1];
        float r  = w00 * v00.x + w10 * v10.x + w01 * v01.x + w11 * v11.x;
        float g  = w00 * v00.y + w10 * v10.y + w01 * v01.y + w11 * v11.y;
        float b2 = w00 * v00.z + w10 * v10.z + w01 * v01.z + w11 * v11.z;
        float m  = w00 * v00.w + w10 * v10.w + w01 * v01.w + w11 * v11.w;
        r = clip01(r * bf);
        g = clip01(g * bf);
        b2 = clip01(b2 * bf);
        rr[k] = r; gg[k] = g; bb[k] = b2; mm[k] = m;
        grays += 0.299f * r + 0.587f * g + 0.114f * b2;
    }
    {
        size_t pix = (size_t)(by + ty) * Wd + bx + 2 * tx2;       // even
        unsigned short* pb = pre + (size_t)b * 3 * PLANE;
        *(unsigned*)(pb + pix)             = pack2h(rr[0], rr[1]);
        *(unsigned*)(pb + PLANE + pix)     = pack2h(gg[0], gg[1]);
        *(unsigned*)(pb + 2 * PLANE + pix) = pack2h(bb[0], bb[1]);
        *(float2*)(omasks + (size_t)b * PLANE + pix) = make_float2(mm[0], mm[1]);
    }

    __syncthreads();
    float* sred = (float*)tile;
    sred[tid] = grays;
    __syncthreads();
    for (int off = 128; off > 0; off >>= 1) {
        if (tid < off) sred[tid] += sred[tid + off];
        __syncthreads();
    }
    if (tid == 0)
        partials[(size_t)b * 512 + blockIdx.y * 16 + blockIdx.x] = sred[0];
}

__global__ __launch_bounds__(256) void k_mean(const float* __restrict__ partials,
                                              float* __restrict__ means)
{
    int b = blockIdx.x;
    int t = threadIdx.x;
    float s = partials[(size_t)b * 512 + t] + partials[(size_t)b * 512 + t + 256];
    __shared__ float sr[256];
    sr[t] = s;
    __syncthreads();
    for (int off = 128; off > 0; off >>= 1) {
        if (t < off) sr[t] += sr[t + off];
        __syncthreads();
    }
    if (t == 0) means[b] = sr[0] * (1.f / (float)PLANE);
}

__device__ __forceinline__ void jit1(float& r, float& g, float& bl,
                                     float mean, float cf, float sf, float hsh)
{
    r  = clip01(cf * r + (1.f - cf) * mean);
    g  = clip01(cf * g + (1.f - cf) * mean);
    bl = clip01(cf * bl + (1.f - cf) * mean);

    float gray = 0.299f * r + 0.587f * g + 0.114f * bl;
    r  = clip01(sf * r + (1.f - sf) * gray);
    g  = clip01(sf * g + (1.f - sf) * gray);
    bl = clip01(sf * bl + (1.f - sf) * gray);

    float maxc = fmaxf(fmaxf(r, g), bl);
    float minc = fminf(fminf(r, g), bl);
    float delta = maxc - minc;
    float sgm = delta / (maxc + 1e-8f);
    float dd = delta + 1e-8f;
    float rc = (maxc - r) / dd;
    float gc = (maxc - g) / dd;
    float bc = (maxc - bl) / dd;
    float h6 = (maxc == r) ? (bc - gc) : ((maxc == g) ? (2.f + rc - bc) : (4.f + gc - rc));
    float h = h6 * (1.f / 6.f);
    h = h - floorf(h);
    h = h + hsh;
    h = h - floorf(h);

    float hi = floorf(h * 6.f);
    float f = h * 6.f - hi;
    float v = maxc;
    float p = v * (1.f - sgm);
    float q = v * (1.f - f * sgm);
    float t = v * (1.f - (1.f - f) * sgm);
    int i = ((int)hi) % 6;
    if (i < 0) i += 6;
    float ro, go, bo;
    switch (i) {
        case 0: ro = v; go = t; bo = p; break;
        case 1: ro = q; go = v; bo = p; break;
        case 2: ro = p; go = v; bo = t; break;
        case 3: ro = p; go = q; bo = v; break;
        case 4: ro = t; go = p; bo = v; break;
        default: ro = v; go = p; bo = q; break;
    }
    r = clip01(ro); g = clip01(go); bl = clip01(bo);
}

__global__ __launch_bounds__(256) void k_jitter(const unsigned short* __restrict__ pre,
                                                const float* __restrict__ means,
                                                const float* __restrict__ contrast,
                                                const float* __restrict__ saturation,
                                                const float* __restrict__ hue,
                                                float* __restrict__ oimgs)
{
    int b = blockIdx.y;
    size_t i4 = (size_t)blockIdx.x * 256 + threadIdx.x;   // group of 4 px
    const unsigned short* pb = pre + (size_t)b * 3 * PLANE;

    uint2 ur = *(const uint2*)(pb + i4 * 4);
    uint2 ug = *(const uint2*)(pb + PLANE + i4 * 4);
    uint2 ub = *(const uint2*)(pb + 2 * PLANE + i4 * 4);

    float2 r01 = unp2h(ur.x), r23 = unp2h(ur.y);
    float2 g01 = unp2h(ug.x), g23 = unp2h(ug.y);
    float2 b01 = unp2h(ub.x), b23 = unp2h(ub.y);

    float4 R  = make_float4(r01.x, r01.y, r23.x, r23.y);
    float4 G  = make_float4(g01.x, g01.y, g23.x, g23.y);
    float4 Bv = make_float4(b01.x, b01.y, b23.x, b23.y);

    float mean = means[b];
    float cf = contrast[b], sf = saturation[b], hsh = hue[b];

    jit1(R.x, G.x, Bv.x, mean, cf, sf, hsh);
    jit1(R.y, G.y, Bv.y, mean, cf, sf, hsh);
    jit1(R.z, G.z, Bv.z, mean, cf, sf, hsh);
    jit1(R.w, G.w, Bv.w, mean, cf, sf, hsh);

    size_t po = (size_t)b * 3 * PLANE + i4 * 4;
    *(float4*)(oimgs + po)             = R;
    *(float4*)(oimgs + po + PLANE)     = G;
    *(float4*)(oimgs + po + 2 * PLANE) = Bv;
}

extern "C" void kernel_launch(void* const* d_in, const int* in_sizes, int n_in,
                              void* d_out, int out_size, void* d_ws, size_t ws_size,
                              hipStream_t stream)
{
    const float* imgs       = (const float*)d_in[0];
    const float* masks      = (const float*)d_in[1];
    const int*   hflip      = (const int*)d_in[2];
    const int*   vflip      = (const int*)d_in[3];
    const float* angles     = (const float*)d_in[4];
    const float* translate  = (const float*)d_in[5];
    const float* scale      = (const float*)d_in[6];
    const float* brightness = (const float*)d_in[7];
    const float* contrast   = (const float*)d_in[8];
    const float* saturation = (const float*)d_in[9];
    const float* hue        = (const float*)d_in[10];

    float* oimgs  = (float*)d_out;
    float* omasks = oimgs + (size_t)Bd * 3 * PLANE;

    uint2* rot          = (uint2*)d_ws;                                  // 67 MB
    unsigned short* pre = (unsigned short*)(rot + (size_t)Bd * PLANE);   // 50 MB
    float* partials     = (float*)(pre + (size_t)3 * Bd * PLANE);        // Bd*512
    float* means        = partials + (size_t)Bd * 512;                   // Bd

    dim3 blk1(16, 16);
    dim3 grd1(Wd / 16, Hd / 16, Bd);
    k_rotate<<<grd1, blk1, 0, stream>>>(imgs, masks, hflip, vflip, angles, rot);

    dim3 blk2(16, 16);
    dim3 grd2(Wd / 32, Hd / 16, Bd);
    k_affine<<<grd2, blk2, 0, stream>>>((const ushort4*)rot, translate, scale, brightness,
                                        pre, omasks, partials);

    k_mean<<<Bd, 256, 0, stream>>>(partials, means);

    dim3 grd3(PLANE / 4 / 256, Bd);
    k_jitter<<<grd3, 256, 0, stream>>>(pre, means, contrast, saturation, hue, oimgs);
}

// Round 11
// 149.404 us; speedup vs baseline: 1.0336x; 1.0309x over previous
//
#include <hip/hip_runtime.h>
#include <hip/hip_fp16.h>
#include <math.h>

#define Wd 512
#define Hd 512
#define Bd 32
#define PLANE (Hd * Wd)

// k_rotate: 16x16 output tile; rotated-source window 26 rows x 26 cols (+1 pad
// col -> stride 27). LDS AoS float4 cells. 702 slots = 2*256 + 190.
#define WND 26
#define STR 27
#define NCELL (WND * STR)

// k_affine staging window (AoS float4 cells); scale>=0.9 -> cols<=39, rows<=21
#define RPW 40
#define RPH 22

__device__ __forceinline__ float clip01(float x) { return fminf(fmaxf(x, 0.f), 1.f); }

__device__ __forceinline__ unsigned pack2h(float a, float b) {
    __half2 h = __floats2half2_rn(a, b);
    return *(unsigned*)&h;
}
__device__ __forceinline__ float2 unp2h(unsigned u) {
    return __half22float2(*(__half2*)&u);
}

// ---------------------------------------------------------------------------
// K1: flip + rotate -> AoS fp16 rot. Flips folded as coordinate reflection.
// Staging: 12 UNCONDITIONAL clamped scalar loads (4 planes x 3 slots) issued
// before a sched_barrier(0) fence, then LDS writes -- forces all loads in
// flight (defeats compiler serialization seen as VGPR=16 in R7).
// Zero-padding enforced by validity-weight masking at sample time.
// ---------------------------------------------------------------------------
__global__ __launch_bounds__(256) void k_rotate(const float* __restrict__ imgs,
                                                const float* __restrict__ masks,
                                                const int* __restrict__ hflip,
                                                const int* __restrict__ vflip,
                                                const float* __restrict__ angles,
                                                uint2* __restrict__ rot)
{
    __shared__ float4 tile[NCELL];       // 11232 B

    const int tx = threadIdx.x, ty = threadIdx.y;
    const int tid = ty * 16 + tx;
    const int bx = blockIdx.x * 16, by = blockIdx.y * 16;
    const int b = blockIdx.z;

    const float cx = (Wd - 1) * 0.5f, cy = (Hd - 1) * 0.5f;
    const float th = angles[b] * 0.017453292519943295f;
    const float c = cosf(th), s = sinf(th);
    const bool hf = hflip[b] > 0, vf = vflip[b] > 0;

    // tile-corner bbox (same fp expressions as per-pixel, incl. reflection)
    const float xs0 = (float)bx - cx, xs1 = (float)(bx + 15) - cx;
    const float ys0 = (float)by - cy, ys1 = (float)(by + 15) - cy;
    float a0 = c * xs0 + s * ys0 + cx, a1 = c * xs1 + s * ys0 + cx;
    float a2 = c * xs0 + s * ys1 + cx, a3 = c * xs1 + s * ys1 + cx;
    float b0 = -s * xs0 + c * ys0 + cy, b1 = -s * xs1 + c * ys0 + cy;
    float b2 = -s * xs0 + c * ys1 + cy, b3 = -s * xs1 + c * ys1 + cy;
    float mnx = fminf(fminf(a0, a1), fminf(a2, a3));
    float mxx = fmaxf(fmaxf(a0, a1), fmaxf(a2, a3));
    float mny = fminf(fminf(b0, b1), fminf(b2, b3));
    float mxy = fmaxf(fmaxf(b0, b1), fmaxf(b2, b3));
    const int ox0 = (int)floorf(hf ? (511.f - mxx) : mnx) - 1;
    const int oy0 = (int)floorf(vf ? (511.f - mxy) : mny) - 1;

    const float* ib = imgs + (size_t)b * 3 * PLANE;
    const float* mb = masks + (size_t)b * PLANE;

    // ---- phase 1: compute 3 clamped addresses, issue all 12 loads ----
    const int idx0 = tid, idx1 = tid + 256, idx2 = tid + 512;
    int r0 = idx0 / STR, c0v = idx0 - r0 * STR;
    int r1 = idx1 / STR, c1v = idx1 - r1 * STR;
    int slot2 = min(idx2, NCELL - 1);
    int r2 = slot2 / STR, c2v = slot2 - r2 * STR;

    int gi0 = min(max(oy0 + r0, 0), Hd - 1) * Wd + min(max(ox0 + c0v, 0), Wd - 1);
    int gi1 = min(max(oy0 + r1, 0), Hd - 1) * Wd + min(max(ox0 + c1v, 0), Wd - 1);
    int gi2 = min(max(oy0 + r2, 0), Hd - 1) * Wd + min(max(ox0 + c2v, 0), Wd - 1);

    float4 v0, v1, v2;
    v0.x = ib[gi0]; v0.y = ib[gi0 + PLANE]; v0.z = ib[gi0 + 2 * PLANE]; v0.w = mb[gi0];
    v1.x = ib[gi1]; v1.y = ib[gi1 + PLANE]; v1.z = ib[gi1 + 2 * PLANE]; v1.w = mb[gi1];
    v2.x = ib[gi2]; v2.y = ib[gi2 + PLANE]; v2.z = ib[gi2 + 2 * PLANE]; v2.w = mb[gi2];

    __builtin_amdgcn_sched_barrier(0);   // loads may not sink past this point

    // ---- phase 2: LDS writes ----
    tile[idx0] = v0;
    tile[idx1] = v1;
    if (idx2 < NCELL) tile[idx2] = v2;
    __syncthreads();

    const int x = bx + tx, y = by + ty;
    float dx = (float)x - cx, dy = (float)y - cy;
    float sx = c * dx + s * dy + cx;
    float sy = -s * dx + c * dy + cy;
    if (hf) sx = 511.f - sx;
    if (vf) sy = 511.f - sy;

    float sxl = sx - (float)ox0, syl = sy - (float)oy0;
    float x0f = floorf(sxl), y0f = floorf(syl);
    float wx = sxl - x0f, wy = syl - y0f;
    int xi = min(max((int)x0f, 0), STR - 2);
    int yi = min(max((int)y0f, 0), WND - 2);

    // validity from true source coords (reference's valid-mask semantics)
    float fx0 = (float)ox0 + x0f, fy0 = (float)oy0 + y0f;
    float vx0 = (fx0 >= 0.f && fx0 <= 511.f) ? 1.f : 0.f;
    float vx1 = (fx0 >= -1.f && fx0 <= 510.f) ? 1.f : 0.f;
    float vy0 = (fy0 >= 0.f && fy0 <= 511.f) ? 1.f : 0.f;
    float vy1 = (fy0 >= -1.f && fy0 <= 510.f) ? 1.f : 0.f;
    float w00 = (1.f - wx) * (1.f - wy) * vx0 * vy0;
    float w10 = wx * (1.f - wy) * vx1 * vy0;
    float w01 = (1.f - wx) * wy * vx0 * vy1;
    float w11 = wx * wy * vx1 * vy1;

    int base = yi * STR + xi;
    float4 v00 = tile[base], v10 = tile[base + 1];
    float4 v01 = tile[base + STR], v11 = tile[base + STR + 1];

    float r  = w00 * v00.x + w10 * v10.x + w01 * v01.x + w11 * v11.x;
    float g  = w00 * v00.y + w10 * v10.y + w01 * v01.y + w11 * v11.y;
    float bl = w00 * v00.z + w10 * v10.z + w01 * v01.z + w11 * v11.z;
    float m  = w00 * v00.w + w10 * v10.w + w01 * v01.w + w11 * v11.w;

    rot[(size_t)b * PLANE + (size_t)y * Wd + x] =
        make_uint2(pack2h(r, g), pack2h(bl, m));
}

// ---------------------------------------------------------------------------
// K2: affine from AoS fp16 rot + brightness (register staging, R7-proven).
// Writes masks (final f32) to d_out, rgb as packed fp16 planes to ws, partials.
// ---------------------------------------------------------------------------
__global__ __launch_bounds__(256) void k_affine(const ushort4* __restrict__ rot,
                                                const float* __restrict__ translate,
                                                const float* __restrict__ scale,
                                                const float* __restrict__ brightness,
                                                unsigned short* __restrict__ pre,
                                                float* __restrict__ omasks,
                                                float* __restrict__ partials)
{
    __shared__ float4 tile[RPH * RPW];     // 14080 B

    const int tx2 = threadIdx.x;           // 0..15
    const int ty  = threadIdx.y;           // 0..15
    const int tid = ty * 16 + tx2;
    const int bx = blockIdx.x * 32, by = blockIdx.y * 16;
    const int b = blockIdx.z;

    const float cx = (Wd - 1) * 0.5f, cy = (Hd - 1) * 0.5f;
    const float txf = translate[2 * b] * (float)Wd;
    const float tyf = translate[2 * b + 1] * (float)Hd;
    const float sc = scale[b];
    const float bf = brightness[b];

    float ax0 = ((float)bx - cx - txf) / sc + cx;
    float ax1 = ((float)(bx + 31) - cx - txf) / sc + cx;
    float ay0 = ((float)by - cy - tyf) / sc + cy;
    float ay1 = ((float)(by + 15) - cy - tyf) / sc + cy;
    const int rx0 = (int)floorf(fminf(ax0, ax1)) - 1;
    const int ry0 = (int)floorf(fminf(ay0, ay1)) - 1;

    const ushort4* srcp = rot + (size_t)b * PLANE;
    const bool fastp = (rx0 >= 0) && (ry0 >= 0) &&
                       (rx0 + RPW <= Wd) && (ry0 + RPH <= Hd);

    if (fastp) {
        for (int idx = tid; idx < RPH * RPW; idx += 256) {
            int row = idx / RPW;
            int col = idx - row * RPW;
            ushort4 h = srcp[(ry0 + row) * Wd + rx0 + col];
            tile[idx] = make_float4(__half2float(__ushort_as_half(h.x)),
                                    __half2float(__ushort_as_half(h.y)),
                                    __half2float(__ushort_as_half(h.z)),
                                    __half2float(__ushort_as_half(h.w)));
        }
    } else {
        for (int idx = tid; idx < RPH * RPW; idx += 256) {
            int row = idx / RPW;
            int col = idx - row * RPW;
            int gy = ry0 + row, gx = rx0 + col;
            float4 v = make_float4(0.f, 0.f, 0.f, 0.f);
            if ((unsigned)gy < (unsigned)Hd && (unsigned)gx < (unsigned)Wd) {
                ushort4 h = srcp[gy * Wd + gx];
                v = make_float4(__half2float(__ushort_as_half(h.x)),
                                __half2float(__ushort_as_half(h.y)),
                                __half2float(__ushort_as_half(h.z)),
                                __half2float(__ushort_as_half(h.w)));
            }
            tile[idx] = v;
        }
    }
    __syncthreads();

    float grays = 0.f;
    float rr[2], gg[2], bb[2], mm[2];
    #pragma unroll
    for (int k = 0; k < 2; ++k) {
        int x = bx + 2 * tx2 + k, y = by + ty;
        float sx = ((float)x - cx - txf) / sc + cx;
        float sy = ((float)y - cy - tyf) / sc + cy;
        float sxl = sx - (float)rx0, syl = sy - (float)ry0;
        float x0f = floorf(sxl), y0f = floorf(syl);
        float wx = sxl - x0f, wy = syl - y0f;
        int xi = min(max((int)x0f, 0), RPW - 2);
        int yi = min(max((int)y0f, 0), RPH - 2);
        float w00 = (1.f - wx) * (1.f - wy);
        float w10 = wx * (1.f - wy);
        float w01 = (1.f - wx) * wy;
        float w11 = wx * wy;
        int base = yi * RPW + xi;
        float4 v00 = tile[base], v10 = tile[base + 1];
        float4 v01 = tile[base + RPW], v11 = tile[base + RPW + 1];
        float r  = w00 * v00.x + w10 * v10.x + w01 * v01.x + w11 * v11.x;
        float g  = w00 * v00.y + w10 * v10.y + w01 * v01.y + w11 * v11.y;
        float b2 = w00 * v00.z + w10 * v10.z + w01 * v01.z + w11 * v11.z;
        float m  = w00 * v00.w + w10 * v10.w + w01 * v01.w + w11 * v11.w;
        r = clip01(r * bf);
        g = clip01(g * bf);
        b2 = clip01(b2 * bf);
        rr[k] = r; gg[k] = g; bb[k] = b2; mm[k] = m;
        grays += 0.299f * r + 0.587f * g + 0.114f * b2;
    }
    {
        size_t pix = (size_t)(by + ty) * Wd + bx + 2 * tx2;       // even
        unsigned short* pb = pre + (size_t)b * 3 * PLANE;
        *(unsigned*)(pb + pix)             = pack2h(rr[0], rr[1]);
        *(unsigned*)(pb + PLANE + pix)     = pack2h(gg[0], gg[1]);
        *(unsigned*)(pb + 2 * PLANE + pix) = pack2h(bb[0], bb[1]);
        *(float2*)(omasks + (size_t)b * PLANE + pix) = make_float2(mm[0], mm[1]);
    }

    __syncthreads();
    float* sred = (float*)tile;
    sred[tid] = grays;
    __syncthreads();
    for (int off = 128; off > 0; off >>= 1) {
        if (tid < off) sred[tid] += sred[tid + off];
        __syncthreads();
    }
    if (tid == 0)
        partials[(size_t)b * 512 + blockIdx.y * 16 + blockIdx.x] = sred[0];
}

__global__ __launch_bounds__(256) void k_mean(const float* __restrict__ partials,
                                              float* __restrict__ means)
{
    int b = blockIdx.x;
    int t = threadIdx.x;
    float s = partials[(size_t)b * 512 + t] + partials[(size_t)b * 512 + t + 256];
    __shared__ float sr[256];
    sr[t] = s;
    __syncthreads();
    for (int off = 128; off > 0; off >>= 1) {
        if (t < off) sr[t] += sr[t + off];
        __syncthreads();
    }
    if (t == 0) means[b] = sr[0] * (1.f / (float)PLANE);
}

__device__ __forceinline__ void jit1(float& r, float& g, float& bl,
                                     float mean, float cf, float sf, float hsh)
{
    r  = clip01(cf * r + (1.f - cf) * mean);
    g  = clip01(cf * g + (1.f - cf) * mean);
    bl = clip01(cf * bl + (1.f - cf) * mean);

    float gray = 0.299f * r + 0.587f * g + 0.114f * bl;
    r  = clip01(sf * r + (1.f - sf) * gray);
    g  = clip01(sf * g + (1.f - sf) * gray);
    bl = clip01(sf * bl + (1.f - sf) * gray);

    float maxc = fmaxf(fmaxf(r, g), bl);
    float minc = fminf(fminf(r, g), bl);
    float delta = maxc - minc;
    float sgm = delta / (maxc + 1e-8f);
    float dd = delta + 1e-8f;
    float rc = (maxc - r) / dd;
    float gc = (maxc - g) / dd;
    float bc = (maxc - bl) / dd;
    float h6 = (maxc == r) ? (bc - gc) : ((maxc == g) ? (2.f + rc - bc) : (4.f + gc - rc));
    float h = h6 * (1.f / 6.f);
    h = h - floorf(h);
    h = h + hsh;
    h = h - floorf(h);

    float hi = floorf(h * 6.f);
    float f = h * 6.f - hi;
    float v = maxc;
    float p = v * (1.f - sgm);
    float q = v * (1.f - f * sgm);
    float t = v * (1.f - (1.f - f) * sgm);
    int i = ((int)hi) % 6;
    if (i < 0) i += 6;
    float ro, go, bo;
    switch (i) {
        case 0: ro = v; go = t; bo = p; break;
        case 1: ro = q; go = v; bo = p; break;
        case 2: ro = p; go = v; bo = t; break;
        case 3: ro = p; go = q; bo = v; break;
        case 4: ro = t; go = p; bo = v; break;
        default: ro = v; go = p; bo = q; break;
    }
    r = clip01(ro); g = clip01(go); bl = clip01(bo);
}

__global__ __launch_bounds__(256) void k_jitter(const unsigned short* __restrict__ pre,
                                                const float* __restrict__ means,
                                                const float* __restrict__ contrast,
                                                const float* __restrict__ saturation,
                                                const float* __restrict__ hue,
                                                float* __restrict__ oimgs)
{
    int b = blockIdx.y;
    size_t i4 = (size_t)blockIdx.x * 256 + threadIdx.x;   // group of 4 px
    const unsigned short* pb = pre + (size_t)b * 3 * PLANE;

    uint2 ur = *(const uint2*)(pb + i4 * 4);
    uint2 ug = *(const uint2*)(pb + PLANE + i4 * 4);
    uint2 ub = *(const uint2*)(pb + 2 * PLANE + i4 * 4);

    float2 r01 = unp2h(ur.x), r23 = unp2h(ur.y);
    float2 g01 = unp2h(ug.x), g23 = unp2h(ug.y);
    float2 b01 = unp2h(ub.x), b23 = unp2h(ub.y);

    float4 R  = make_float4(r01.x, r01.y, r23.x, r23.y);
    float4 G  = make_float4(g01.x, g01.y, g23.x, g23.y);
    float4 Bv = make_float4(b01.x, b01.y, b23.x, b23.y);

    float mean = means[b];
    float cf = contrast[b], sf = saturation[b], hsh = hue[b];

    jit1(R.x, G.x, Bv.x, mean, cf, sf, hsh);
    jit1(R.y, G.y, Bv.y, mean, cf, sf, hsh);
    jit1(R.z, G.z, Bv.z, mean, cf, sf, hsh);
    jit1(R.w, G.w, Bv.w, mean, cf, sf, hsh);

    size_t po = (size_t)b * 3 * PLANE + i4 * 4;
    *(float4*)(oimgs + po)             = R;
    *(float4*)(oimgs + po + PLANE)     = G;
    *(float4*)(oimgs + po + 2 * PLANE) = Bv;
}

extern "C" void kernel_launch(void* const* d_in, const int* in_sizes, int n_in,
                              void* d_out, int out_size, void* d_ws, size_t ws_size,
                              hipStream_t stream)
{
    const float* imgs       = (const float*)d_in[0];
    const float* masks      = (const float*)d_in[1];
    const int*   hflip      = (const int*)d_in[2];
    const int*   vflip      = (const int*)d_in[3];
    const float* angles     = (const float*)d_in[4];
    const float* translate  = (const float*)d_in[5];
    const float* scale      = (const float*)d_in[6];
    const float* brightness = (const float*)d_in[7];
    const float* contrast   = (const float*)d_in[8];
    const float* saturation = (const float*)d_in[9];
    const float* hue        = (const float*)d_in[10];

    float* oimgs  = (float*)d_out;
    float* omasks = oimgs + (size_t)Bd * 3 * PLANE;

    uint2* rot          = (uint2*)d_ws;                                  // 67 MB
    unsigned short* pre = (unsigned short*)(rot + (size_t)Bd * PLANE);   // 50 MB
    float* partials     = (float*)(pre + (size_t)3 * Bd * PLANE);        // Bd*512
    float* means        = partials + (size_t)Bd * 512;                   // Bd

    dim3 blk1(16, 16);
    dim3 grd1(Wd / 16, Hd / 16, Bd);
    k_rotate<<<grd1, blk1, 0, stream>>>(imgs, masks, hflip, vflip, angles, rot);

    dim3 blk2(16, 16);
    dim3 grd2(Wd / 32, Hd / 16, Bd);
    k_affine<<<grd2, blk2, 0, stream>>>((const ushort4*)rot, translate, scale, brightness,
                                        pre, omasks, partials);

    k_mean<<<Bd, 256, 0, stream>>>(partials, means);

    dim3 grd3(PLANE / 4 / 256, Bd);
    k_jitter<<<grd3, 256, 0, stream>>>(pre, means, contrast, saturation, hue, oimgs);
}

// Round 12
// 128.750 us; speedup vs baseline: 1.1994x; 1.1604x over previous
//
#include <hip/hip_runtime.h>
#include <hip/hip_fp16.h>
#include <math.h>

#define Wd 512
#define Hd 512
#define Bd 32
#define PLANE (Hd * Wd)

// k_rotate: 32x32 output tile, 4 px/thread. Rotated-source window 48x48
// (span 31*sqrt2=43.8 +1 bilinear +2 guard = 47 -> 48), fp16 AoS uint2 cells,
// row stride 49 (odd) -> conflict-free. 48*49*8B = 18816 B LDS.
#define WIN 48
#define WSTR 49

// k_affine staging window (AoS float4 cells); scale>=0.9 -> cols<=39, rows<=21
#define RPW 40
#define RPH 22

__device__ __forceinline__ float clip01(float x) { return fminf(fmaxf(x, 0.f), 1.f); }

__device__ __forceinline__ unsigned pack2h(float a, float b) {
    __half2 h = __floats2half2_rn(a, b);
    return *(unsigned*)&h;
}
__device__ __forceinline__ float2 unp2h(unsigned u) {
    return __half22float2(*(__half2*)&u);
}

// ---------------------------------------------------------------------------
// K1: flip + rotate -> AoS fp16 rot. Flips folded as coordinate reflection.
// 32x32 tile: staging ratio 2.30 cells/px (vs 2.74 at 16x16). XCD-bijective
// block swizzle gives each XCD 4 contiguous images -> tile row-overlap hits
// its own L2 instead of re-fetching from HBM. Clamped staging addresses;
// zero-padding enforced by validity-weight masking at sample time.
// ---------------------------------------------------------------------------
__global__ __launch_bounds__(256) void k_rotate(const float* __restrict__ imgs,
                                                const float* __restrict__ masks,
                                                const int* __restrict__ hflip,
                                                const int* __restrict__ vflip,
                                                const float* __restrict__ angles,
                                                uint2* __restrict__ rot)
{
    __shared__ uint2 cells[WIN * WSTR];        // 18816 B

    // bijective XCD swizzle: nwg = 32*16*16 = 8192, 8192/8 = 1024 per XCD
    const int hw = blockIdx.x;
    const int lt = (hw & 7) * 1024 + (hw >> 3);
    const int b   = lt >> 8;                   // 256 tiles per image
    const int t   = lt & 255;
    const int bx  = (t & 15) * 32;
    const int by  = (t >> 4) * 32;

    const int tx = threadIdx.x, ty = threadIdx.y;   // (32,8)
    const int tid = ty * 32 + tx;

    const float cx = (Wd - 1) * 0.5f, cy = (Hd - 1) * 0.5f;
    const float th = angles[b] * 0.017453292519943295f;
    const float c = cosf(th), s = sinf(th);
    const bool hf = hflip[b] > 0, vf = vflip[b] > 0;

    // tile-corner bbox (same fp expressions as per-pixel, incl. reflection)
    const float xs0 = (float)bx - cx, xs1 = (float)(bx + 31) - cx;
    const float ys0 = (float)by - cy, ys1 = (float)(by + 31) - cy;
    float a0 = c * xs0 + s * ys0 + cx, a1 = c * xs1 + s * ys0 + cx;
    float a2 = c * xs0 + s * ys1 + cx, a3 = c * xs1 + s * ys1 + cx;
    float b0 = -s * xs0 + c * ys0 + cy, b1 = -s * xs1 + c * ys0 + cy;
    float b2 = -s * xs0 + c * ys1 + cy, b3 = -s * xs1 + c * ys1 + cy;
    float mnx = fminf(fminf(a0, a1), fminf(a2, a3));
    float mxx = fmaxf(fmaxf(a0, a1), fmaxf(a2, a3));
    float mny = fminf(fminf(b0, b1), fminf(b2, b3));
    float mxy = fmaxf(fmaxf(b0, b1), fmaxf(b2, b3));
    const int ox0 = (int)floorf(hf ? (511.f - mxx) : mnx) - 1;
    const int oy0 = (int)floorf(vf ? (511.f - mxy) : mny) - 1;

    const float* ib = imgs + (size_t)b * 3 * PLANE;
    const float* mb = masks + (size_t)b * PLANE;

    // ---- staging: 2304 cells = 9 full iters; 4 clamped scalar loads/cell ----
    #pragma unroll
    for (int it = 0; it < 9; ++it) {
        int slot = tid + it * 256;
        int row = slot / WIN;
        int col = slot - row * WIN;
        int gi = min(max(oy0 + row, 0), Hd - 1) * Wd + min(max(ox0 + col, 0), Wd - 1);
        float r = ib[gi];
        float g = ib[gi + PLANE];
        float bl = ib[gi + 2 * PLANE];
        float m = mb[gi];
        cells[row * WSTR + col] = make_uint2(pack2h(r, g), pack2h(bl, m));
    }
    __syncthreads();

    // ---- 4 px/thread sampling ----
    #pragma unroll
    for (int k = 0; k < 4; ++k) {
        const int x = bx + tx, y = by + ty + k * 8;
        float dx = (float)x - cx, dy = (float)y - cy;
        float sx = c * dx + s * dy + cx;
        float sy = -s * dx + c * dy + cy;
        if (hf) sx = 511.f - sx;
        if (vf) sy = 511.f - sy;

        float sxl = sx - (float)ox0, syl = sy - (float)oy0;
        float x0f = floorf(sxl), y0f = floorf(syl);
        float wx = sxl - x0f, wy = syl - y0f;
        int xi = min(max((int)x0f, 0), WIN - 2);
        int yi = min(max((int)y0f, 0), WIN - 2);

        // validity from true source coords (reference's valid-mask semantics)
        float fx0 = (float)ox0 + x0f, fy0 = (float)oy0 + y0f;
        float vx0 = (fx0 >= 0.f && fx0 <= 511.f) ? 1.f : 0.f;
        float vx1 = (fx0 >= -1.f && fx0 <= 510.f) ? 1.f : 0.f;
        float vy0 = (fy0 >= 0.f && fy0 <= 511.f) ? 1.f : 0.f;
        float vy1 = (fy0 >= -1.f && fy0 <= 510.f) ? 1.f : 0.f;
        float w00 = (1.f - wx) * (1.f - wy) * vx0 * vy0;
        float w10 = wx * (1.f - wy) * vx1 * vy0;
        float w01 = (1.f - wx) * wy * vx0 * vy1;
        float w11 = wx * wy * vx1 * vy1;

        int base = yi * WSTR + xi;
        uint2 c00 = cells[base],        c10 = cells[base + 1];
        uint2 c01 = cells[base + WSTR], c11 = cells[base + WSTR + 1];

        float2 rg00 = unp2h(c00.x), bm00 = unp2h(c00.y);
        float2 rg10 = unp2h(c10.x), bm10 = unp2h(c10.y);
        float2 rg01 = unp2h(c01.x), bm01 = unp2h(c01.y);
        float2 rg11 = unp2h(c11.x), bm11 = unp2h(c11.y);

        float r  = w00 * rg00.x + w10 * rg10.x + w01 * rg01.x + w11 * rg11.x;
        float g  = w00 * rg00.y + w10 * rg10.y + w01 * rg01.y + w11 * rg11.y;
        float bl = w00 * bm00.x + w10 * bm10.x + w01 * bm01.x + w11 * bm11.x;
        float m  = w00 * bm00.y + w10 * bm10.y + w01 * bm01.y + w11 * bm11.y;

        rot[(size_t)b * PLANE + (size_t)y * Wd + x] =
            make_uint2(pack2h(r, g), pack2h(bl, m));
    }
}

// ---------------------------------------------------------------------------
// K2: affine from AoS fp16 rot + brightness (register staging, R7-proven).
// Writes masks (final f32) to d_out, rgb as packed fp16 planes to ws, partials.
// ---------------------------------------------------------------------------
__global__ __launch_bounds__(256) void k_affine(const ushort4* __restrict__ rot,
                                                const float* __restrict__ translate,
                                                const float* __restrict__ scale,
                                                const float* __restrict__ brightness,
                                                unsigned short* __restrict__ pre,
                                                float* __restrict__ omasks,
                                                float* __restrict__ partials)
{
    __shared__ float4 tile[RPH * RPW];     // 14080 B

    const int tx2 = threadIdx.x;           // 0..15
    const int ty  = threadIdx.y;           // 0..15
    const int tid = ty * 16 + tx2;
    const int bx = blockIdx.x * 32, by = blockIdx.y * 16;
    const int b = blockIdx.z;

    const float cx = (Wd - 1) * 0.5f, cy = (Hd - 1) * 0.5f;
    const float txf = translate[2 * b] * (float)Wd;
    const float tyf = translate[2 * b + 1] * (float)Hd;
    const float sc = scale[b];
    const float bf = brightness[b];

    float ax0 = ((float)bx - cx - txf) / sc + cx;
    float ax1 = ((float)(bx + 31) - cx - txf) / sc + cx;
    float ay0 = ((float)by - cy - tyf) / sc + cy;
    float ay1 = ((float)(by + 15) - cy - tyf) / sc + cy;
    const int rx0 = (int)floorf(fminf(ax0, ax1)) - 1;
    const int ry0 = (int)floorf(fminf(ay0, ay1)) - 1;

    const ushort4* srcp = rot + (size_t)b * PLANE;
    const bool fastp = (rx0 >= 0) && (ry0 >= 0) &&
                       (rx0 + RPW <= Wd) && (ry0 + RPH <= Hd);

    if (fastp) {
        for (int idx = tid; idx < RPH * RPW; idx += 256) {
            int row = idx / RPW;
            int col = idx - row * RPW;
            ushort4 h = srcp[(ry0 + row) * Wd + rx0 + col];
            tile[idx] = make_float4(__half2float(__ushort_as_half(h.x)),
                                    __half2float(__ushort_as_half(h.y)),
                                    __half2float(__ushort_as_half(h.z)),
                                    __half2float(__ushort_as_half(h.w)));
        }
    } else {
        for (int idx = tid; idx < RPH * RPW; idx += 256) {
            int row = idx / RPW;
            int col = idx - row * RPW;
            int gy = ry0 + row, gx = rx0 + col;
            float4 v = make_float4(0.f, 0.f, 0.f, 0.f);
            if ((unsigned)gy < (unsigned)Hd && (unsigned)gx < (unsigned)Wd) {
                ushort4 h = srcp[gy * Wd + gx];
                v = make_float4(__half2float(__ushort_as_half(h.x)),
                                __half2float(__ushort_as_half(h.y)),
                                __half2float(__ushort_as_half(h.z)),
                                __half2float(__ushort_as_half(h.w)));
            }
            tile[idx] = v;
        }
    }
    __syncthreads();

    float grays = 0.f;
    float rr[2], gg[2], bb[2], mm[2];
    #pragma unroll
    for (int k = 0; k < 2; ++k) {
        int x = bx + 2 * tx2 + k, y = by + ty;
        float sx = ((float)x - cx - txf) / sc + cx;
        float sy = ((float)y - cy - tyf) / sc + cy;
        float sxl = sx - (float)rx0, syl = sy - (float)ry0;
        float x0f = floorf(sxl), y0f = floorf(syl);
        float wx = sxl - x0f, wy = syl - y0f;
        int xi = min(max((int)x0f, 0), RPW - 2);
        int yi = min(max((int)y0f, 0), RPH - 2);
        float w00 = (1.f - wx) * (1.f - wy);
        float w10 = wx * (1.f - wy);
        float w01 = (1.f - wx) * wy;
        float w11 = wx * wy;
        int base = yi * RPW + xi;
        float4 v00 = tile[base], v10 = tile[base + 1];
        float4 v01 = tile[base + RPW], v11 = tile[base + RPW + 1];
        float r  = w00 * v00.x + w10 * v10.x + w01 * v01.x + w11 * v11.x;
        float g  = w00 * v00.y + w10 * v10.y + w01 * v01.y + w11 * v11.y;
        float b2 = w00 * v00.z + w10 * v10.z + w01 * v01.z + w11 * v11.z;
        float m  = w00 * v00.w + w10 * v10.w + w01 * v01.w + w11 * v11.w;
        r = clip01(r * bf);
        g = clip01(g * bf);
        b2 = clip01(b2 * bf);
        rr[k] = r; gg[k] = g; bb[k] = b2; mm[k] = m;
        grays += 0.299f * r + 0.587f * g + 0.114f * b2;
    }
    {
        size_t pix = (size_t)(by + ty) * Wd + bx + 2 * tx2;       // even
        unsigned short* pb = pre + (size_t)b * 3 * PLANE;
        *(unsigned*)(pb + pix)             = pack2h(rr[0], rr[1]);
        *(unsigned*)(pb + PLANE + pix)     = pack2h(gg[0], gg[1]);
        *(unsigned*)(pb + 2 * PLANE + pix) = pack2h(bb[0], bb[1]);
        *(float2*)(omasks + (size_t)b * PLANE + pix) = make_float2(mm[0], mm[1]);
    }

    __syncthreads();
    float* sred = (float*)tile;
    sred[tid] = grays;
    __syncthreads();
    for (int off = 128; off > 0; off >>= 1) {
        if (tid < off) sred[tid] += sred[tid + off];
        __syncthreads();
    }
    if (tid == 0)
        partials[(size_t)b * 512 + blockIdx.y * 16 + blockIdx.x] = sred[0];
}

__global__ __launch_bounds__(256) void k_mean(const float* __restrict__ partials,
                                              float* __restrict__ means)
{
    int b = blockIdx.x;
    int t = threadIdx.x;
    float s = partials[(size_t)b * 512 + t] + partials[(size_t)b * 512 + t + 256];
    __shared__ float sr[256];
    sr[t] = s;
    __syncthreads();
    for (int off = 128; off > 0; off >>= 1) {
        if (t < off) sr[t] += sr[t + off];
        __syncthreads();
    }
    if (t == 0) means[b] = sr[0] * (1.f / (float)PLANE);
}

__device__ __forceinline__ void jit1(float& r, float& g, float& bl,
                                     float mean, float cf, float sf, float hsh)
{
    r  = clip01(cf * r + (1.f - cf) * mean);
    g  = clip01(cf * g + (1.f - cf) * mean);
    bl = clip01(cf * bl + (1.f - cf) * mean);

    float gray = 0.299f * r + 0.587f * g + 0.114f * bl;
    r  = clip01(sf * r + (1.f - sf) * gray);
    g  = clip01(sf * g + (1.f - sf) * gray);
    bl = clip01(sf * bl + (1.f - sf) * gray);

    float maxc = fmaxf(fmaxf(r, g), bl);
    float minc = fminf(fminf(r, g), bl);
    float delta = maxc - minc;
    float sgm = delta / (maxc + 1e-8f);
    float dd = delta + 1e-8f;
    float rc = (maxc - r) / dd;
    float gc = (maxc - g) / dd;
    float bc = (maxc - bl) / dd;
    float h6 = (maxc == r) ? (bc - gc) : ((maxc == g) ? (2.f + rc - bc) : (4.f + gc - rc));
    float h = h6 * (1.f / 6.f);
    h = h - floorf(h);
    h = h + hsh;
    h = h - floorf(h);

    float hi = floorf(h * 6.f);
    float f = h * 6.f - hi;
    float v = maxc;
    float p = v * (1.f - sgm);
    float q = v * (1.f - f * sgm);
    float t = v * (1.f - (1.f - f) * sgm);
    int i = ((int)hi) % 6;
    if (i < 0) i += 6;
    float ro, go, bo;
    switch (i) {
        case 0: ro = v; go = t; bo = p; break;
        case 1: ro = q; go = v; bo = p; break;
        case 2: ro = p; go = v; bo = t; break;
        case 3: ro = p; go = q; bo = v; break;
        case 4: ro = t; go = p; bo = v; break;
        default: ro = v; go = p; bo = q; break;
    }
    r = clip01(ro); g = clip01(go); bl = clip01(bo);
}

__global__ __launch_bounds__(256) void k_jitter(const unsigned short* __restrict__ pre,
                                                const float* __restrict__ means,
                                                const float* __restrict__ contrast,
                                                const float* __restrict__ saturation,
                                                const float* __restrict__ hue,
                                                float* __restrict__ oimgs)
{
    int b = blockIdx.y;
    size_t i4 = (size_t)blockIdx.x * 256 + threadIdx.x;   // group of 4 px
    const unsigned short* pb = pre + (size_t)b * 3 * PLANE;

    uint2 ur = *(const uint2*)(pb + i4 * 4);
    uint2 ug = *(const uint2*)(pb + PLANE + i4 * 4);
    uint2 ub = *(const uint2*)(pb + 2 * PLANE + i4 * 4);

    float2 r01 = unp2h(ur.x), r23 = unp2h(ur.y);
    float2 g01 = unp2h(ug.x), g23 = unp2h(ug.y);
    float2 b01 = unp2h(ub.x), b23 = unp2h(ub.y);

    float4 R  = make_float4(r01.x, r01.y, r23.x, r23.y);
    float4 G  = make_float4(g01.x, g01.y, g23.x, g23.y);
    float4 Bv = make_float4(b01.x, b01.y, b23.x, b23.y);

    float mean = means[b];
    float cf = contrast[b], sf = saturation[b], hsh = hue[b];

    jit1(R.x, G.x, Bv.x, mean, cf, sf, hsh);
    jit1(R.y, G.y, Bv.y, mean, cf, sf, hsh);
    jit1(R.z, G.z, Bv.z, mean, cf, sf, hsh);
    jit1(R.w, G.w, Bv.w, mean, cf, sf, hsh);

    size_t po = (size_t)b * 3 * PLANE + i4 * 4;
    *(float4*)(oimgs + po)             = R;
    *(float4*)(oimgs + po + PLANE)     = G;
    *(float4*)(oimgs + po + 2 * PLANE) = Bv;
}

extern "C" void kernel_launch(void* const* d_in, const int* in_sizes, int n_in,
                              void* d_out, int out_size, void* d_ws, size_t ws_size,
                              hipStream_t stream)
{
    const float* imgs       = (const float*)d_in[0];
    const float* masks      = (const float*)d_in[1];
    const int*   hflip      = (const int*)d_in[2];
    const int*   vflip      = (const int*)d_in[3];
    const float* angles     = (const float*)d_in[4];
    const float* translate  = (const float*)d_in[5];
    const float* scale      = (const float*)d_in[6];
    const float* brightness = (const float*)d_in[7];
    const float* contrast   = (const float*)d_in[8];
    const float* saturation = (const float*)d_in[9];
    const float* hue        = (const float*)d_in[10];

    float* oimgs  = (float*)d_out;
    float* omasks = oimgs + (size_t)Bd * 3 * PLANE;

    uint2* rot          = (uint2*)d_ws;                                  // 67 MB
    unsigned short* pre = (unsigned short*)(rot + (size_t)Bd * PLANE);   // 50 MB
    float* partials     = (float*)(pre + (size_t)3 * Bd * PLANE);        // Bd*512
    float* means        = partials + (size_t)Bd * 512;                   // Bd

    dim3 blk1(32, 8);
    dim3 grd1(Bd * 16 * 16);          // 8192 blocks, XCD-swizzled inside
    k_rotate<<<grd1, blk1, 0, stream>>>(imgs, masks, hflip, vflip, angles, rot);

    dim3 blk2(16, 16);
    dim3 grd2(Wd / 32, Hd / 16, Bd);
    k_affine<<<grd2, blk2, 0, stream>>>((const ushort4*)rot, translate, scale, brightness,
                                        pre, omasks, partials);

    k_mean<<<Bd, 256, 0, stream>>>(partials, means);

    dim3 grd3(PLANE / 4 / 256, Bd);
    k_jitter<<<grd3, 256, 0, stream>>>(pre, means, contrast, saturation, hue, oimgs);
}

// Round 13
// 118.028 us; speedup vs baseline: 1.3084x; 1.0908x over previous
//
#include <hip/hip_runtime.h>
#include <hip/hip_fp16.h>
#include <math.h>

#define Wd 512
#define Hd 512
#define Bd 32
#define PLANE (Hd * Wd)

// k_rotate: 32x32 output tile, 4 px/thread. Window 48x48 fp16 AoS uint2 cells,
// row stride 50 (EVEN: required so pair-writes are 16B-aligned b128).
// 48*50*8B = 19200 B LDS. Staging = float2-per-plane pair loads (18 loads vs
// 36 scalar) + one uint4 LDS write per 2-cell pair (canonical pattern).
#define WIN 48
#define WSTR 50
#define NPR1 (WIN * (WIN / 2))   // 1152 pairs

// k_affine: 32x32 output tile. Window 40 rows x 40 cols uint2 cells,
// stride 42 (even). 40*42*8 = 13440 B. 800 pairs.
#define AWIN 40
#define ASTR 42
#define NPR2 (AWIN * (AWIN / 2))  // 800

__device__ __forceinline__ float clip01(float x) { return fminf(fmaxf(x, 0.f), 1.f); }

__device__ __forceinline__ unsigned pack2h(float a, float b) {
    __half2 h = __floats2half2_rn(a, b);
    return *(unsigned*)&h;
}
__device__ __forceinline__ float2 unp2h(unsigned u) {
    return __half22float2(*(__half2*)&u);
}

// ---------------------------------------------------------------------------
// K1: flip + rotate -> AoS fp16 rot. Coordinate-reflection flips, XCD swizzle,
// clamped pair staging + validity-weight masking (all R12-proven).
// ---------------------------------------------------------------------------
__global__ __launch_bounds__(256) void k_rotate(const float* __restrict__ imgs,
                                                const float* __restrict__ masks,
                                                const int* __restrict__ hflip,
                                                const int* __restrict__ vflip,
                                                const float* __restrict__ angles,
                                                uint2* __restrict__ rot)
{
    __shared__ uint2 cells[WIN * WSTR];        // 19200 B

    // bijective XCD swizzle: nwg = 8192, 1024 per XCD (4 contiguous images)
    const int hw = blockIdx.x;
    const int lt = (hw & 7) * 1024 + (hw >> 3);
    const int b   = lt >> 8;
    const int t   = lt & 255;
    const int bx  = (t & 15) * 32;
    const int by  = (t >> 4) * 32;

    const int tx = threadIdx.x, ty = threadIdx.y;   // (32,8)
    const int tid = ty * 32 + tx;

    const float cx = (Wd - 1) * 0.5f, cy = (Hd - 1) * 0.5f;
    const float th = angles[b] * 0.017453292519943295f;
    const float c = cosf(th), s = sinf(th);
    const bool hf = hflip[b] > 0, vf = vflip[b] > 0;

    const float xs0 = (float)bx - cx, xs1 = (float)(bx + 31) - cx;
    const float ys0 = (float)by - cy, ys1 = (float)(by + 31) - cy;
    float a0 = c * xs0 + s * ys0 + cx, a1 = c * xs1 + s * ys0 + cx;
    float a2 = c * xs0 + s * ys1 + cx, a3 = c * xs1 + s * ys1 + cx;
    float b0 = -s * xs0 + c * ys0 + cy, b1 = -s * xs1 + c * ys0 + cy;
    float b2 = -s * xs0 + c * ys1 + cy, b3 = -s * xs1 + c * ys1 + cy;
    float mnx = fminf(fminf(a0, a1), fminf(a2, a3));
    float mxx = fmaxf(fmaxf(a0, a1), fmaxf(a2, a3));
    float mny = fminf(fminf(b0, b1), fminf(b2, b3));
    float mxy = fmaxf(fmaxf(b0, b1), fmaxf(b2, b3));
    const int ox0 = ((int)floorf(hf ? (511.f - mxx) : mnx) - 1) & ~1;  // even
    const int oy0 = (int)floorf(vf ? (511.f - mxy) : mny) - 1;

    const float* ib = imgs + (size_t)b * 3 * PLANE;
    const float* mb = masks + (size_t)b * PLANE;

    // ---- staging: 1152 pairs; per pair: 4x float2 load + 1x uint4 LDS write
    #pragma unroll
    for (int it = 0; it < 5; ++it) {
        int slot = tid + it * 256;
        if (it < 4 || slot < NPR1) {
            int row = slot / (WIN / 2);
            int pc  = slot - row * (WIN / 2);
            int gy = min(max(oy0 + row, 0), Hd - 1);
            int gx = min(max(ox0 + 2 * pc, 0), Wd - 2) & ~1;
            int gi = gy * Wd + gx;
            float2 r2 = *(const float2*)(ib + gi);
            float2 g2 = *(const float2*)(ib + gi + PLANE);
            float2 b2v = *(const float2*)(ib + gi + 2 * PLANE);
            float2 m2 = *(const float2*)(mb + gi);
            uint4 w;
            w.x = pack2h(r2.x, g2.x);
            w.y = pack2h(b2v.x, m2.x);
            w.z = pack2h(r2.y, g2.y);
            w.w = pack2h(b2v.y, m2.y);
            *(uint4*)&cells[row * WSTR + 2 * pc] = w;   // 16B-aligned (WSTR even)
        }
    }
    __syncthreads();

    // ---- 4 px/thread sampling ----
    #pragma unroll
    for (int k = 0; k < 4; ++k) {
        const int x = bx + tx, y = by + ty + k * 8;
        float dx = (float)x - cx, dy = (float)y - cy;
        float sx = c * dx + s * dy + cx;
        float sy = -s * dx + c * dy + cy;
        if (hf) sx = 511.f - sx;
        if (vf) sy = 511.f - sy;

        float sxl = sx - (float)ox0, syl = sy - (float)oy0;
        float x0f = floorf(sxl), y0f = floorf(syl);
        float wx = sxl - x0f, wy = syl - y0f;
        int xi = min(max((int)x0f, 0), WIN - 2);
        int yi = min(max((int)y0f, 0), WIN - 2);

        float fx0 = (float)ox0 + x0f, fy0 = (float)oy0 + y0f;
        float vx0 = (fx0 >= 0.f && fx0 <= 511.f) ? 1.f : 0.f;
        float vx1 = (fx0 >= -1.f && fx0 <= 510.f) ? 1.f : 0.f;
        float vy0 = (fy0 >= 0.f && fy0 <= 511.f) ? 1.f : 0.f;
        float vy1 = (fy0 >= -1.f && fy0 <= 510.f) ? 1.f : 0.f;
        float w00 = (1.f - wx) * (1.f - wy) * vx0 * vy0;
        float w10 = wx * (1.f - wy) * vx1 * vy0;
        float w01 = (1.f - wx) * wy * vx0 * vy1;
        float w11 = wx * wy * vx1 * vy1;

        int base = yi * WSTR + xi;
        uint2 c00 = cells[base],        c10 = cells[base + 1];
        uint2 c01 = cells[base + WSTR], c11 = cells[base + WSTR + 1];

        float2 rg00 = unp2h(c00.x), bm00 = unp2h(c00.y);
        float2 rg10 = unp2h(c10.x), bm10 = unp2h(c10.y);
        float2 rg01 = unp2h(c01.x), bm01 = unp2h(c01.y);
        float2 rg11 = unp2h(c11.x), bm11 = unp2h(c11.y);

        float r  = w00 * rg00.x + w10 * rg10.x + w01 * rg01.x + w11 * rg11.x;
        float g  = w00 * rg00.y + w10 * rg10.y + w01 * rg01.y + w11 * rg11.y;
        float bl = w00 * bm00.x + w10 * bm10.x + w01 * bm01.x + w11 * bm11.x;
        float m  = w00 * bm00.y + w10 * bm10.y + w01 * bm01.y + w11 * bm11.y;

        rot[(size_t)b * PLANE + (size_t)y * Wd + x] =
            make_uint2(pack2h(r, g), pack2h(bl, m));
    }
}

// ---------------------------------------------------------------------------
// K2: affine from AoS fp16 rot + brightness. 32x32 tile, XCD swizzle, clamped
// uint4 pair staging + validity masking (no divergent paths). Writes masks
// (final f32) to d_out, rgb as packed fp16 planes to ws, 256 partials/image.
// ---------------------------------------------------------------------------
__global__ __launch_bounds__(256) void k_affine(const uint2* __restrict__ rot,
                                                const float* __restrict__ translate,
                                                const float* __restrict__ scale,
                                                const float* __restrict__ brightness,
                                                unsigned short* __restrict__ pre,
                                                float* __restrict__ omasks,
                                                float* __restrict__ partials)
{
    __shared__ uint2 tile[AWIN * ASTR];      // 13440 B

    const int hw = blockIdx.x;
    const int lt = (hw & 7) * 1024 + (hw >> 3);
    const int b   = lt >> 8;
    const int t   = lt & 255;
    const int bx  = (t & 15) * 32;
    const int by  = (t >> 4) * 32;

    const int tx2 = threadIdx.x;             // 0..15
    const int ty  = threadIdx.y;             // 0..15
    const int tid = ty * 16 + tx2;

    const float cx = (Wd - 1) * 0.5f, cy = (Hd - 1) * 0.5f;
    const float txf = translate[2 * b] * (float)Wd;
    const float tyf = translate[2 * b + 1] * (float)Hd;
    const float sc = scale[b];
    const float bf = brightness[b];

    float ax0 = ((float)bx - cx - txf) / sc + cx;
    float ax1 = ((float)(bx + 31) - cx - txf) / sc + cx;
    float ay0 = ((float)by - cy - tyf) / sc + cy;
    float ay1 = ((float)(by + 31) - cy - tyf) / sc + cy;
    const int rx0 = (((int)floorf(fminf(ax0, ax1)) - 1) & ~1);   // even
    const int ry0 = (int)floorf(fminf(ay0, ay1)) - 1;

    const uint2* sb = rot + (size_t)b * PLANE;

    // ---- staging: 800 pairs, uint4 loads (2 cells) + aligned uint4 writes ----
    #pragma unroll
    for (int it = 0; it < 4; ++it) {
        int slot = tid + it * 256;
        if (it < 3 || slot < NPR2) {
            int row = slot / (AWIN / 2);
            int pc  = slot - row * (AWIN / 2);
            int gy = min(max(ry0 + row, 0), Hd - 1);
            int gx = min(max(rx0 + 2 * pc, 0), Wd - 2) & ~1;
            uint4 v = *(const uint4*)(sb + gy * Wd + gx);
            *(uint4*)&tile[row * ASTR + 2 * pc] = v;     // 16B-aligned (ASTR even)
        }
    }
    __syncthreads();

    float grays = 0.f;
    #pragma unroll
    for (int j = 0; j < 2; ++j) {
        float rr[2], gg[2], bb[2], mm[2];
        const int y = by + ty + 16 * j;
        #pragma unroll
        for (int k = 0; k < 2; ++k) {
            int x = bx + 2 * tx2 + k;
            float sx = ((float)x - cx - txf) / sc + cx;
            float sy = ((float)y - cy - tyf) / sc + cy;
            float sxl = sx - (float)rx0, syl = sy - (float)ry0;
            float x0f = floorf(sxl), y0f = floorf(syl);
            float wx = sxl - x0f, wy = syl - y0f;
            int xi = min(max((int)x0f, 0), AWIN - 2);
            int yi = min(max((int)y0f, 0), AWIN - 2);

            float fx0 = (float)rx0 + x0f, fy0 = (float)ry0 + y0f;
            float vx0 = (fx0 >= 0.f && fx0 <= 511.f) ? 1.f : 0.f;
            float vx1 = (fx0 >= -1.f && fx0 <= 510.f) ? 1.f : 0.f;
            float vy0 = (fy0 >= 0.f && fy0 <= 511.f) ? 1.f : 0.f;
            float vy1 = (fy0 >= -1.f && fy0 <= 510.f) ? 1.f : 0.f;
            float w00 = (1.f - wx) * (1.f - wy) * vx0 * vy0;
            float w10 = wx * (1.f - wy) * vx1 * vy0;
            float w01 = (1.f - wx) * wy * vx0 * vy1;
            float w11 = wx * wy * vx1 * vy1;

            int base = yi * ASTR + xi;
            uint2 c00 = tile[base],        c10 = tile[base + 1];
            uint2 c01 = tile[base + ASTR], c11 = tile[base + ASTR + 1];
            float2 rg00 = unp2h(c00.x), bm00 = unp2h(c00.y);
            float2 rg10 = unp2h(c10.x), bm10 = unp2h(c10.y);
            float2 rg01 = unp2h(c01.x), bm01 = unp2h(c01.y);
            float2 rg11 = unp2h(c11.x), bm11 = unp2h(c11.y);

            float r  = w00 * rg00.x + w10 * rg10.x + w01 * rg01.x + w11 * rg11.x;
            float g  = w00 * rg00.y + w10 * rg10.y + w01 * rg01.y + w11 * rg11.y;
            float b2 = w00 * bm00.x + w10 * bm10.x + w01 * bm01.x + w11 * bm11.x;
            float m  = w00 * bm00.y + w10 * bm10.y + w01 * bm01.y + w11 * bm11.y;

            r = clip01(r * bf);
            g = clip01(g * bf);
            b2 = clip01(b2 * bf);
            rr[k] = r; gg[k] = g; bb[k] = b2; mm[k] = m;
            grays += 0.299f * r + 0.587f * g + 0.114f * b2;
        }
        size_t pix = (size_t)y * Wd + bx + 2 * tx2;       // even
        unsigned short* pb = pre + (size_t)b * 3 * PLANE;
        *(unsigned*)(pb + pix)             = pack2h(rr[0], rr[1]);
        *(unsigned*)(pb + PLANE + pix)     = pack2h(gg[0], gg[1]);
        *(unsigned*)(pb + 2 * PLANE + pix) = pack2h(bb[0], bb[1]);
        *(float2*)(omasks + (size_t)b * PLANE + pix) = make_float2(mm[0], mm[1]);
    }

    __syncthreads();
    float* sred = (float*)tile;
    sred[tid] = grays;
    __syncthreads();
    for (int off = 128; off > 0; off >>= 1) {
        if (tid < off) sred[tid] += sred[tid + off];
        __syncthreads();
    }
    if (tid == 0)
        partials[(size_t)b * 256 + t] = sred[0];
}

__global__ __launch_bounds__(256) void k_mean(const float* __restrict__ partials,
                                              float* __restrict__ means)
{
    int b = blockIdx.x;
    int t = threadIdx.x;
    float s = partials[(size_t)b * 256 + t];
    __shared__ float sr[256];
    sr[t] = s;
    __syncthreads();
    for (int off = 128; off > 0; off >>= 1) {
        if (t < off) sr[t] += sr[t + off];
        __syncthreads();
    }
    if (t == 0) means[b] = sr[0] * (1.f / (float)PLANE);
}

__device__ __forceinline__ void jit1(float& r, float& g, float& bl,
                                     float mean, float cf, float sf, float hsh)
{
    r  = clip01(cf * r + (1.f - cf) * mean);
    g  = clip01(cf * g + (1.f - cf) * mean);
    bl = clip01(cf * bl + (1.f - cf) * mean);

    float gray = 0.299f * r + 0.587f * g + 0.114f * bl;
    r  = clip01(sf * r + (1.f - sf) * gray);
    g  = clip01(sf * g + (1.f - sf) * gray);
    bl = clip01(sf * bl + (1.f - sf) * gray);

    float maxc = fmaxf(fmaxf(r, g), bl);
    float minc = fminf(fminf(r, g), bl);
    float delta = maxc - minc;
    float sgm = delta / (maxc + 1e-8f);
    float dd = delta + 1e-8f;
    float rc = (maxc - r) / dd;
    float gc = (maxc - g) / dd;
    float bc = (maxc - bl) / dd;
    float h6 = (maxc == r) ? (bc - gc) : ((maxc == g) ? (2.f + rc - bc) : (4.f + gc - rc));
    float h = h6 * (1.f / 6.f);
    h = h - floorf(h);
    h = h + hsh;
    h = h - floorf(h);

    float hi = floorf(h * 6.f);
    float f = h * 6.f - hi;
    float v = maxc;
    float p = v * (1.f - sgm);
    float q = v * (1.f - f * sgm);
    float t = v * (1.f - (1.f - f) * sgm);
    int i = ((int)hi) % 6;
    if (i < 0) i += 6;
    float ro, go, bo;
    switch (i) {
        case 0: ro = v; go = t; bo = p; break;
        case 1: ro = q; go = v; bo = p; break;
        case 2: ro = p; go = v; bo = t; break;
        case 3: ro = p; go = q; bo = v; break;
        case 4: ro = t; go = p; bo = v; break;
        default: ro = v; go = p; bo = q; break;
    }
    r = clip01(ro); g = clip01(go); bl = clip01(bo);
}

__global__ __launch_bounds__(256) void k_jitter(const unsigned short* __restrict__ pre,
                                                const float* __restrict__ means,
                                                const float* __restrict__ contrast,
                                                const float* __restrict__ saturation,
                                                const float* __restrict__ hue,
                                                float* __restrict__ oimgs)
{
    int b = blockIdx.y;
    size_t i4 = (size_t)blockIdx.x * 256 + threadIdx.x;   // group of 4 px
    const unsigned short* pb = pre + (size_t)b * 3 * PLANE;

    uint2 ur = *(const uint2*)(pb + i4 * 4);
    uint2 ug = *(const uint2*)(pb + PLANE + i4 * 4);
    uint2 ub = *(const uint2*)(pb + 2 * PLANE + i4 * 4);

    float2 r01 = unp2h(ur.x), r23 = unp2h(ur.y);
    float2 g01 = unp2h(ug.x), g23 = unp2h(ug.y);
    float2 b01 = unp2h(ub.x), b23 = unp2h(ub.y);

    float4 R  = make_float4(r01.x, r01.y, r23.x, r23.y);
    float4 G  = make_float4(g01.x, g01.y, g23.x, g23.y);
    float4 Bv = make_float4(b01.x, b01.y, b23.x, b23.y);

    float mean = means[b];
    float cf = contrast[b], sf = saturation[b], hsh = hue[b];

    jit1(R.x, G.x, Bv.x, mean, cf, sf, hsh);
    jit1(R.y, G.y, Bv.y, mean, cf, sf, hsh);
    jit1(R.z, G.z, Bv.z, mean, cf, sf, hsh);
    jit1(R.w, G.w, Bv.w, mean, cf, sf, hsh);

    size_t po = (size_t)b * 3 * PLANE + i4 * 4;
    *(float4*)(oimgs + po)             = R;
    *(float4*)(oimgs + po + PLANE)     = G;
    *(float4*)(oimgs + po + 2 * PLANE) = Bv;
}

extern "C" void kernel_launch(void* const* d_in, const int* in_sizes, int n_in,
                              void* d_out, int out_size, void* d_ws, size_t ws_size,
                              hipStream_t stream)
{
    const float* imgs       = (const float*)d_in[0];
    const float* masks      = (const float*)d_in[1];
    const int*   hflip      = (const int*)d_in[2];
    const int*   vflip      = (const int*)d_in[3];
    const float* angles     = (const float*)d_in[4];
    const float* translate  = (const float*)d_in[5];
    const float* scale      = (const float*)d_in[6];
    const float* brightness = (const float*)d_in[7];
    const float* contrast   = (const float*)d_in[8];
    const float* saturation = (const float*)d_in[9];
    const float* hue        = (const float*)d_in[10];

    float* oimgs  = (float*)d_out;
    float* omasks = oimgs + (size_t)Bd * 3 * PLANE;

    uint2* rot          = (uint2*)d_ws;                                  // 67 MB
    unsigned short* pre = (unsigned short*)(rot + (size_t)Bd * PLANE);   // 50 MB
    float* partials     = (float*)(pre + (size_t)3 * Bd * PLANE);        // Bd*256
    float* means        = partials + (size_t)Bd * 256;                   // Bd

    dim3 blk1(32, 8);
    dim3 grd1(Bd * 16 * 16);          // 8192 blocks, XCD-swizzled inside
    k_rotate<<<grd1, blk1, 0, stream>>>(imgs, masks, hflip, vflip, angles, rot);

    dim3 blk2(16, 16);
    dim3 grd2(Bd * 16 * 16);          // 8192 blocks, XCD-swizzled inside
    k_affine<<<grd2, blk2, 0, stream>>>(rot, translate, scale, brightness,
                                        pre, omasks, partials);

    k_mean<<<Bd, 256, 0, stream>>>(partials, means);

    dim3 grd3(PLANE / 4 / 256, Bd);
    k_jitter<<<grd3, 256, 0, stream>>>(pre, means, contrast, saturation, hue, oimgs);
}

// Round 14
// 116.102 us; speedup vs baseline: 1.3301x; 1.0166x over previous
//
#include <hip/hip_runtime.h>
#include <hip/hip_fp16.h>
#include <math.h>

#define Wd 512
#define Hd 512
#define Bd 32
#define PLANE (Hd * Wd)

// k_rotate: 32x32 output tile, 4 px/thread. Window 48 rows x 52 cols (4-aligned
// origin + slack), fp16 AoS uint2 cells, row stride 54 (row*54*8B = 27*16B ->
// quad writes stay 16B-aligned). 48*54*8B = 20736 B LDS.
// Staging: float4-per-plane QUAD loads (4 cells): 4 loads + 2 uint4 writes/slot.
#define WINR 48
#define WINC 52
#define WSTR 54
#define NQ1 (WINR * (WINC / 4))   // 624 quad slots

// k_affine: 32x32 output tile. Window 40x40 uint2 cells, stride 42 (even).
#define AWIN 40
#define ASTR 42
#define NPR2 (AWIN * (AWIN / 2))  // 800

__device__ __forceinline__ float clip01(float x) { return fminf(fmaxf(x, 0.f), 1.f); }

__device__ __forceinline__ unsigned pack2h(float a, float b) {
    __half2 h = __floats2half2_rn(a, b);
    return *(unsigned*)&h;
}
__device__ __forceinline__ float2 unp2h(unsigned u) {
    return __half22float2(*(__half2*)&u);
}

// ---------------------------------------------------------------------------
// K1: flip + rotate -> AoS fp16 rot. Coordinate-reflection flips, XCD swizzle,
// clamped QUAD staging + validity-weight masking.
// ---------------------------------------------------------------------------
__global__ __launch_bounds__(256) void k_rotate(const float* __restrict__ imgs,
                                                const float* __restrict__ masks,
                                                const int* __restrict__ hflip,
                                                const int* __restrict__ vflip,
                                                const float* __restrict__ angles,
                                                uint2* __restrict__ rot)
{
    __shared__ uint2 cells[WINR * WSTR];       // 20736 B

    // bijective XCD swizzle: nwg = 8192, 1024 per XCD (4 contiguous images)
    const int hw = blockIdx.x;
    const int lt = (hw & 7) * 1024 + (hw >> 3);
    const int b   = lt >> 8;
    const int t   = lt & 255;
    const int bx  = (t & 15) * 32;
    const int by  = (t >> 4) * 32;

    const int tx = threadIdx.x, ty = threadIdx.y;   // (32,8)
    const int tid = ty * 32 + tx;

    const float cx = (Wd - 1) * 0.5f, cy = (Hd - 1) * 0.5f;
    const float th = angles[b] * 0.017453292519943295f;
    const float c = cosf(th), s = sinf(th);
    const bool hf = hflip[b] > 0, vf = vflip[b] > 0;

    const float xs0 = (float)bx - cx, xs1 = (float)(bx + 31) - cx;
    const float ys0 = (float)by - cy, ys1 = (float)(by + 31) - cy;
    float a0 = c * xs0 + s * ys0 + cx, a1 = c * xs1 + s * ys0 + cx;
    float a2 = c * xs0 + s * ys1 + cx, a3 = c * xs1 + s * ys1 + cx;
    float b0 = -s * xs0 + c * ys0 + cy, b1 = -s * xs1 + c * ys0 + cy;
    float b2 = -s * xs0 + c * ys1 + cy, b3 = -s * xs1 + c * ys1 + cy;
    float mnx = fminf(fminf(a0, a1), fminf(a2, a3));
    float mxx = fmaxf(fmaxf(a0, a1), fmaxf(a2, a3));
    float mny = fminf(fminf(b0, b1), fminf(b2, b3));
    float mxy = fmaxf(fmaxf(b0, b1), fmaxf(b2, b3));
    const int ox0 = ((int)floorf(hf ? (511.f - mxx) : mnx) - 1) & ~3;  // 4-aligned
    const int oy0 = (int)floorf(vf ? (511.f - mxy) : mny) - 1;

    const float* ib = imgs + (size_t)b * 3 * PLANE;
    const float* mb = masks + (size_t)b * PLANE;

    // ---- staging: 624 quads; per quad: 4x float4 load + 2x uint4 LDS write
    #pragma unroll
    for (int it = 0; it < 3; ++it) {
        int slot = tid + it * 256;
        if (it < 2 || slot < NQ1) {
            int row = slot / (WINC / 4);
            int qc  = slot - row * (WINC / 4);
            int gy = min(max(oy0 + row, 0), Hd - 1);
            int gx = min(max(ox0 + 4 * qc, 0), Wd - 4);   // stays 4-aligned
            int gi = gy * Wd + gx;
            float4 r4 = *(const float4*)(ib + gi);
            float4 g4 = *(const float4*)(ib + gi + PLANE);
            float4 b4 = *(const float4*)(ib + gi + 2 * PLANE);
            float4 m4 = *(const float4*)(mb + gi);
            uint4 w0, w1;
            w0.x = pack2h(r4.x, g4.x); w0.y = pack2h(b4.x, m4.x);
            w0.z = pack2h(r4.y, g4.y); w0.w = pack2h(b4.y, m4.y);
            w1.x = pack2h(r4.z, g4.z); w1.y = pack2h(b4.z, m4.z);
            w1.z = pack2h(r4.w, g4.w); w1.w = pack2h(b4.w, m4.w);
            uint2* cp = &cells[row * WSTR + 4 * qc];
            *(uint4*)cp       = w0;       // 16B-aligned (row*54*8 = 27*16*row)
            *(uint4*)(cp + 2) = w1;
        }
    }
    __syncthreads();

    // ---- 4 px/thread sampling ----
    #pragma unroll
    for (int k = 0; k < 4; ++k) {
        const int x = bx + tx, y = by + ty + k * 8;
        float dx = (float)x - cx, dy = (float)y - cy;
        float sx = c * dx + s * dy + cx;
        float sy = -s * dx + c * dy + cy;
        if (hf) sx = 511.f - sx;
        if (vf) sy = 511.f - sy;

        float sxl = sx - (float)ox0, syl = sy - (float)oy0;
        float x0f = floorf(sxl), y0f = floorf(syl);
        float wx = sxl - x0f, wy = syl - y0f;
        int xi = min(max((int)x0f, 0), WINC - 2);
        int yi = min(max((int)y0f, 0), WINR - 2);

        float fx0 = (float)ox0 + x0f, fy0 = (float)oy0 + y0f;
        float vx0 = (fx0 >= 0.f && fx0 <= 511.f) ? 1.f : 0.f;
        float vx1 = (fx0 >= -1.f && fx0 <= 510.f) ? 1.f : 0.f;
        float vy0 = (fy0 >= 0.f && fy0 <= 511.f) ? 1.f : 0.f;
        float vy1 = (fy0 >= -1.f && fy0 <= 510.f) ? 1.f : 0.f;
        float w00 = (1.f - wx) * (1.f - wy) * vx0 * vy0;
        float w10 = wx * (1.f - wy) * vx1 * vy0;
        float w01 = (1.f - wx) * wy * vx0 * vy1;
        float w11 = wx * wy * vx1 * vy1;

        int base = yi * WSTR + xi;
        uint2 c00 = cells[base],        c10 = cells[base + 1];
        uint2 c01 = cells[base + WSTR], c11 = cells[base + WSTR + 1];

        float2 rg00 = unp2h(c00.x), bm00 = unp2h(c00.y);
        float2 rg10 = unp2h(c10.x), bm10 = unp2h(c10.y);
        float2 rg01 = unp2h(c01.x), bm01 = unp2h(c01.y);
        float2 rg11 = unp2h(c11.x), bm11 = unp2h(c11.y);

        float r  = w00 * rg00.x + w10 * rg10.x + w01 * rg01.x + w11 * rg11.x;
        float g  = w00 * rg00.y + w10 * rg10.y + w01 * rg01.y + w11 * rg11.y;
        float bl = w00 * bm00.x + w10 * bm10.x + w01 * bm01.x + w11 * bm11.x;
        float m  = w00 * bm00.y + w10 * bm10.y + w01 * bm01.y + w11 * bm11.y;

        rot[(size_t)b * PLANE + (size_t)y * Wd + x] =
            make_uint2(pack2h(r, g), pack2h(bl, m));
    }
}

// ---------------------------------------------------------------------------
// K2: affine from AoS fp16 rot + brightness (R13-proven). Writes masks (final
// f32) to d_out, rgb as packed fp16 planes to ws, 256 partials/image.
// ---------------------------------------------------------------------------
__global__ __launch_bounds__(256) void k_affine(const uint2* __restrict__ rot,
                                                const float* __restrict__ translate,
                                                const float* __restrict__ scale,
                                                const float* __restrict__ brightness,
                                                unsigned short* __restrict__ pre,
                                                float* __restrict__ omasks,
                                                float* __restrict__ partials)
{
    __shared__ uint2 tile[AWIN * ASTR];      // 13440 B

    const int hw = blockIdx.x;
    const int lt = (hw & 7) * 1024 + (hw >> 3);
    const int b   = lt >> 8;
    const int t   = lt & 255;
    const int bx  = (t & 15) * 32;
    const int by  = (t >> 4) * 32;

    const int tx2 = threadIdx.x;             // 0..15
    const int ty  = threadIdx.y;             // 0..15
    const int tid = ty * 16 + tx2;

    const float cx = (Wd - 1) * 0.5f, cy = (Hd - 1) * 0.5f;
    const float txf = translate[2 * b] * (float)Wd;
    const float tyf = translate[2 * b + 1] * (float)Hd;
    const float sc = scale[b];
    const float bf = brightness[b];

    float ax0 = ((float)bx - cx - txf) / sc + cx;
    float ax1 = ((float)(bx + 31) - cx - txf) / sc + cx;
    float ay0 = ((float)by - cy - tyf) / sc + cy;
    float ay1 = ((float)(by + 31) - cy - tyf) / sc + cy;
    const int rx0 = (((int)floorf(fminf(ax0, ax1)) - 1) & ~1);   // even
    const int ry0 = (int)floorf(fminf(ay0, ay1)) - 1;

    const uint2* sb = rot + (size_t)b * PLANE;

    #pragma unroll
    for (int it = 0; it < 4; ++it) {
        int slot = tid + it * 256;
        if (it < 3 || slot < NPR2) {
            int row = slot / (AWIN / 2);
            int pc  = slot - row * (AWIN / 2);
            int gy = min(max(ry0 + row, 0), Hd - 1);
            int gx = min(max(rx0 + 2 * pc, 0), Wd - 2) & ~1;
            uint4 v = *(const uint4*)(sb + gy * Wd + gx);
            *(uint4*)&tile[row * ASTR + 2 * pc] = v;
        }
    }
    __syncthreads();

    float grays = 0.f;
    #pragma unroll
    for (int j = 0; j < 2; ++j) {
        float rr[2], gg[2], bb[2], mm[2];
        const int y = by + ty + 16 * j;
        #pragma unroll
        for (int k = 0; k < 2; ++k) {
            int x = bx + 2 * tx2 + k;
            float sx = ((float)x - cx - txf) / sc + cx;
            float sy = ((float)y - cy - tyf) / sc + cy;
            float sxl = sx - (float)rx0, syl = sy - (float)ry0;
            float x0f = floorf(sxl), y0f = floorf(syl);
            float wx = sxl - x0f, wy = syl - y0f;
            int xi = min(max((int)x0f, 0), AWIN - 2);
            int yi = min(max((int)y0f, 0), AWIN - 2);

            float fx0 = (float)rx0 + x0f, fy0 = (float)ry0 + y0f;
            float vx0 = (fx0 >= 0.f && fx0 <= 511.f) ? 1.f : 0.f;
            float vx1 = (fx0 >= -1.f && fx0 <= 510.f) ? 1.f : 0.f;
            float vy0 = (fy0 >= 0.f && fy0 <= 511.f) ? 1.f : 0.f;
            float vy1 = (fy0 >= -1.f && fy0 <= 510.f) ? 1.f : 0.f;
            float w00 = (1.f - wx) * (1.f - wy) * vx0 * vy0;
            float w10 = wx * (1.f - wy) * vx1 * vy0;
            float w01 = (1.f - wx) * wy * vx0 * vy1;
            float w11 = wx * wy * vx1 * vy1;

            int base = yi * ASTR + xi;
            uint2 c00 = tile[base],        c10 = tile[base + 1];
            uint2 c01 = tile[base + ASTR], c11 = tile[base + ASTR + 1];
            float2 rg00 = unp2h(c00.x), bm00 = unp2h(c00.y);
            float2 rg10 = unp2h(c10.x), bm10 = unp2h(c10.y);
            float2 rg01 = unp2h(c01.x), bm01 = unp2h(c01.y);
            float2 rg11 = unp2h(c11.x), bm11 = unp2h(c11.y);

            float r  = w00 * rg00.x + w10 * rg10.x + w01 * rg01.x + w11 * rg11.x;
            float g  = w00 * rg00.y + w10 * rg10.y + w01 * rg01.y + w11 * rg11.y;
            float b2 = w00 * bm00.x + w10 * bm10.x + w01 * bm01.x + w11 * bm11.x;
            float m  = w00 * bm00.y + w10 * bm10.y + w01 * bm01.y + w11 * bm11.y;

            r = clip01(r * bf);
            g = clip01(g * bf);
            b2 = clip01(b2 * bf);
            rr[k] = r; gg[k] = g; bb[k] = b2; mm[k] = m;
            grays += 0.299f * r + 0.587f * g + 0.114f * b2;
        }
        size_t pix = (size_t)y * Wd + bx + 2 * tx2;       // even
        unsigned short* pb = pre + (size_t)b * 3 * PLANE;
        *(unsigned*)(pb + pix)             = pack2h(rr[0], rr[1]);
        *(unsigned*)(pb + PLANE + pix)     = pack2h(gg[0], gg[1]);
        *(unsigned*)(pb + 2 * PLANE + pix) = pack2h(bb[0], bb[1]);
        *(float2*)(omasks + (size_t)b * PLANE + pix) = make_float2(mm[0], mm[1]);
    }

    __syncthreads();
    float* sred = (float*)tile;
    sred[tid] = grays;
    __syncthreads();
    for (int off = 128; off > 0; off >>= 1) {
        if (tid < off) sred[tid] += sred[tid + off];
        __syncthreads();
    }
    if (tid == 0)
        partials[(size_t)b * 256 + t] = sred[0];
}

__device__ __forceinline__ void jit1(float& r, float& g, float& bl,
                                     float mean, float cf, float sf, float hsh)
{
    r  = clip01(cf * r + (1.f - cf) * mean);
    g  = clip01(cf * g + (1.f - cf) * mean);
    bl = clip01(cf * bl + (1.f - cf) * mean);

    float gray = 0.299f * r + 0.587f * g + 0.114f * bl;
    r  = clip01(sf * r + (1.f - sf) * gray);
    g  = clip01(sf * g + (1.f - sf) * gray);
    bl = clip01(sf * bl + (1.f - sf) * gray);

    float maxc = fmaxf(fmaxf(r, g), bl);
    float minc = fminf(fminf(r, g), bl);
    float delta = maxc - minc;
    float sgm = delta / (maxc + 1e-8f);
    float dd = delta + 1e-8f;
    float rc = (maxc - r) / dd;
    float gc = (maxc - g) / dd;
    float bc = (maxc - bl) / dd;
    float h6 = (maxc == r) ? (bc - gc) : ((maxc == g) ? (2.f + rc - bc) : (4.f + gc - rc));
    float h = h6 * (1.f / 6.f);
    h = h - floorf(h);
    h = h + hsh;
    h = h - floorf(h);

    float hi = floorf(h * 6.f);
    float f = h * 6.f - hi;
    float v = maxc;
    float p = v * (1.f - sgm);
    float q = v * (1.f - f * sgm);
    float t = v * (1.f - (1.f - f) * sgm);
    int i = ((int)hi) % 6;
    if (i < 0) i += 6;
    float ro, go, bo;
    switch (i) {
        case 0: ro = v; go = t; bo = p; break;
        case 1: ro = q; go = v; bo = p; break;
        case 2: ro = p; go = v; bo = t; break;
        case 3: ro = p; go = q; bo = v; break;
        case 4: ro = t; go = p; bo = v; break;
        default: ro = v; go = p; bo = q; break;
    }
    r = clip01(ro); g = clip01(go); bl = clip01(bo);
}

// K3: jitter, with the per-image mean reduced in-block from the 256 partials
// (identical tree to the old k_mean -> bit-identical) and XCD swizzle matching
// k_affine so pre reads hit the producing XCD's L2.
__global__ __launch_bounds__(256) void k_jitter(const unsigned short* __restrict__ pre,
                                                const float* __restrict__ partials,
                                                const float* __restrict__ contrast,
                                                const float* __restrict__ saturation,
                                                const float* __restrict__ hue,
                                                float* __restrict__ oimgs)
{
    const int hw = blockIdx.x;
    const int lt = (hw & 7) * 1024 + (hw >> 3);
    const int b   = lt >> 8;
    const int blk = lt & 255;
    const int tid = threadIdx.x;

    // in-block mean: same reduction tree as the old k_mean
    __shared__ float sr[256];
    sr[tid] = partials[(size_t)b * 256 + tid];
    __syncthreads();
    for (int off = 128; off > 0; off >>= 1) {
        if (tid < off) sr[tid] += sr[tid + off];
        __syncthreads();
    }
    float mean = sr[0] * (1.f / (float)PLANE);

    size_t i4 = (size_t)blk * 256 + tid;                  // group of 4 px
    const unsigned short* pb = pre + (size_t)b * 3 * PLANE;

    uint2 ur = *(const uint2*)(pb + i4 * 4);
    uint2 ug = *(const uint2*)(pb + PLANE + i4 * 4);
    uint2 ub = *(const uint2*)(pb + 2 * PLANE + i4 * 4);

    float2 r01 = unp2h(ur.x), r23 = unp2h(ur.y);
    float2 g01 = unp2h(ug.x), g23 = unp2h(ug.y);
    float2 b01 = unp2h(ub.x), b23 = unp2h(ub.y);

    float4 R  = make_float4(r01.x, r01.y, r23.x, r23.y);
    float4 G  = make_float4(g01.x, g01.y, g23.x, g23.y);
    float4 Bv = make_float4(b01.x, b01.y, b23.x, b23.y);

    float cf = contrast[b], sf = saturation[b], hsh = hue[b];

    jit1(R.x, G.x, Bv.x, mean, cf, sf, hsh);
    jit1(R.y, G.y, Bv.y, mean, cf, sf, hsh);
    jit1(R.z, G.z, Bv.z, mean, cf, sf, hsh);
    jit1(R.w, G.w, Bv.w, mean, cf, sf, hsh);

    size_t po = (size_t)b * 3 * PLANE + i4 * 4;
    *(float4*)(oimgs + po)             = R;
    *(float4*)(oimgs + po + PLANE)     = G;
    *(float4*)(oimgs + po + 2 * PLANE) = Bv;
}

extern "C" void kernel_launch(void* const* d_in, const int* in_sizes, int n_in,
                              void* d_out, int out_size, void* d_ws, size_t ws_size,
                              hipStream_t stream)
{
    const float* imgs       = (const float*)d_in[0];
    const float* masks      = (const float*)d_in[1];
    const int*   hflip      = (const int*)d_in[2];
    const int*   vflip      = (const int*)d_in[3];
    const float* angles     = (const float*)d_in[4];
    const float* translate  = (const float*)d_in[5];
    const float* scale      = (const float*)d_in[6];
    const float* brightness = (const float*)d_in[7];
    const float* contrast   = (const float*)d_in[8];
    const float* saturation = (const float*)d_in[9];
    const float* hue        = (const float*)d_in[10];

    float* oimgs  = (float*)d_out;
    float* omasks = oimgs + (size_t)Bd * 3 * PLANE;

    uint2* rot          = (uint2*)d_ws;                                  // 67 MB
    unsigned short* pre = (unsigned short*)(rot + (size_t)Bd * PLANE);   // 50 MB
    float* partials     = (float*)(pre + (size_t)3 * Bd * PLANE);        // Bd*256

    dim3 blk1(32, 8);
    dim3 grd1(Bd * 16 * 16);          // 8192 blocks, XCD-swizzled inside
    k_rotate<<<grd1, blk1, 0, stream>>>(imgs, masks, hflip, vflip, angles, rot);

    dim3 blk2(16, 16);
    dim3 grd2(Bd * 16 * 16);
    k_affine<<<grd2, blk2, 0, stream>>>(rot, translate, scale, brightness,
                                        pre, omasks, partials);

    dim3 grd3(Bd * 256);              // 8192 blocks, XCD-swizzled inside
    k_jitter<<<grd3, 256, 0, stream>>>(pre, partials, contrast, saturation, hue, oimgs);
}